// Round 4
// baseline (4279.818 us; speedup 1.0000x reference)
//
#include <hip/hip_runtime.h>
#include <hip/hip_bf16.h>
#include <math.h>

typedef __hip_bfloat16 bf16;

constexpr int B = 16, T = 265, V = 62, F = 5, Kc = 3, FC = 64, FT = 64, KT = 3;
constexpr int VF  = V * F;      // 310
constexpr int VV  = V * V;      // 3844
constexpr int TT  = T * T;      // 70225
constexpr int TVF = T * V * F;  // 82150
constexpr int BT  = B * T;      // 4240
constexpr int CH  = 32;         // t-chunk size
constexpr int RS  = CH + 2;     // ring slots (halo 1 each side)
constexpr int NCHK = (T + CH - 1) / CH;  // 9

// ---------------- workspace layout (float offsets), params first ----------------
constexpr size_t FLAG  = 0;                          // dtype flag (0=bf16,1=f32)
constexpr size_t P_U1  = 4;
constexpr size_t P_U2  = P_U1 + 62;
constexpr size_t P_U3  = P_U2 + 310;
constexpr size_t P_BE  = P_U3 + 5;
constexpr size_t P_VE  = P_BE + 70225;
constexpr size_t P_W1  = P_VE + 70225;
constexpr size_t P_W2  = P_W1 + 265;
constexpr size_t P_W3  = P_W2 + 1325;
constexpr size_t P_BS  = P_W3 + 5;
constexpr size_t P_VS  = P_BS + 3844;
constexpr size_t P_AGL = P_VS + 3844;
constexpr size_t P_THGL= P_AGL + 5;
constexpr size_t P_THSD= P_THGL + 960;
constexpr size_t P_CHEB= P_THSD + 960;               // (K,V,V)
constexpr size_t P_WTGL= P_CHEB + 11532;             // transposed [fc*3+kt][ft]
constexpr size_t P_BCGL= P_WTGL + 12288;
constexpr size_t P_WTSD= P_BCGL + 64;
constexpr size_t P_BCSD= P_WTSD + 12288;
constexpr size_t P_GGL = P_BCSD + 64;
constexpr size_t P_BEGL= P_GGL + 64;
constexpr size_t P_GSD = P_BEGL + 64;
constexpr size_t P_BESD= P_GSD + 64;
constexpr size_t PEND  = (P_BESD + 64 + 3) & ~(size_t)3;
// working buffers
constexpr size_t XF    = PEND;                       // (B,T,V,F) fp32 x
constexpr size_t TLHS  = XF    + (size_t)B*T*V*F;    // (B,T,V)
constexpr size_t TRHS  = TLHS  + (size_t)B*T*V;      // (B,V,T)
constexpr size_t PRODT = TRHS  + (size_t)B*V*T;      // (B,T,T)
constexpr size_t SRAWT = PRODT + (size_t)B*TT;       // (B,T,T) -> TAtt in place
constexpr size_t YBUF  = SRAWT + (size_t)B*TT;       // (B,VF,T) == x_TAtt (B,T,V,F)
constexpr size_t XWOF  = YBUF  + (size_t)B*VF*T;     // (B,V,F)
constexpr size_t SLHS  = XWOF  + (size_t)B*V*F;      // (B,V,T)
constexpr size_t SRHS  = SLHS  + (size_t)B*V*T;      // (B,T,V)
constexpr size_t SATT  = SRHS  + (size_t)B*T*V;      // (B,V,V)
constexpr size_t SPROD = PRODT;                      // alias: PRODT dead after k_sraw
constexpr size_t RING  = SATT  + (size_t)B*V*V;      // (2,B,RS,V,FC)

static __device__ __forceinline__ float sigmoidf_(float x) {
    return 1.f / (1.f + expf(-x));
}

// -------- dtype probe: are inputs bf16 or f32? --------
__global__ void k_dtype(const void* x, float* ws) {
    __shared__ int cnt;
    if (threadIdx.x == 0) cnt = 0;
    __syncthreads();
    int bad = 0;
    const bf16* p = (const bf16*)x;
    for (int i = threadIdx.x; i < 4096; i += 256) {
        float v = __bfloat162float(p[i]);
        if (!isfinite(v) || fabsf(v) > 1e3f || (v != 0.f && fabsf(v) < 1e-10f)) bad++;
    }
    atomicAdd(&cnt, bad);
    __syncthreads();
    if (threadIdx.x == 0) ws[FLAG] = (cnt > 100) ? 1.f : 0.f;
}

static __device__ __forceinline__ void cvtany(const void* s, float* d, int n,
                                              int tid, int st, bool isf) {
    if (isf) {
        const float* p = (const float*)s;
        for (int i = tid; i < n; i += st) d[i] = p[i];
    } else {
        const bf16* p = (const bf16*)s;
        for (int i = tid; i < n; i += st) d[i] = __bfloat162float(p[i]);
    }
}

// -------- convert all inputs to fp32 workspace (Wc transposed) --------
__global__ void k_prep(const void* x, const void* U1, const void* U2, const void* U3,
                       const void* bE, const void* Ve, const void* W1, const void* W2,
                       const void* W3, const void* bS, const void* Vs, const void* aGL,
                       const void* ThGL, const void* ThSD, const void* Cheb,
                       const void* WcGL, const void* bcGL, const void* WcSD, const void* bcSD,
                       const void* gGL, const void* beGL, const void* gSD, const void* beSD,
                       float* ws) {
    int tid = blockIdx.x * blockDim.x + threadIdx.x;
    int st  = gridDim.x * blockDim.x;
    bool isf = ws[FLAG] != 0.f;
    cvtany(x,    ws + XF,    B*T*V*F, tid, st, isf);
    cvtany(U1,   ws + P_U1,  62,    tid, st, isf);
    cvtany(U2,   ws + P_U2,  310,   tid, st, isf);
    cvtany(U3,   ws + P_U3,  5,     tid, st, isf);
    cvtany(bE,   ws + P_BE,  70225, tid, st, isf);
    cvtany(Ve,   ws + P_VE,  70225, tid, st, isf);
    cvtany(W1,   ws + P_W1,  265,   tid, st, isf);
    cvtany(W2,   ws + P_W2,  1325,  tid, st, isf);
    cvtany(W3,   ws + P_W3,  5,     tid, st, isf);
    cvtany(bS,   ws + P_BS,  3844,  tid, st, isf);
    cvtany(Vs,   ws + P_VS,  3844,  tid, st, isf);
    cvtany(aGL,  ws + P_AGL, 5,     tid, st, isf);
    cvtany(ThGL, ws + P_THGL, 960,  tid, st, isf);
    cvtany(ThSD, ws + P_THSD, 960,  tid, st, isf);
    cvtany(Cheb, ws + P_CHEB, 11532, tid, st, isf);
    cvtany(bcGL, ws + P_BCGL, 64, tid, st, isf);
    cvtany(bcSD, ws + P_BCSD, 64, tid, st, isf);
    cvtany(gGL,  ws + P_GGL,  64, tid, st, isf);
    cvtany(beGL, ws + P_BEGL, 64, tid, st, isf);
    cvtany(gSD,  ws + P_GSD,  64, tid, st, isf);
    cvtany(beSD, ws + P_BESD, 64, tid, st, isf);
    // Wc (FT,FC,KT,1) -> [fc*3+kt][ft]
    for (int i = tid; i < 12288; i += st) {
        int ft = i / 192, r = i - ft * 192;
        float g, s;
        if (isf) { g = ((const float*)WcGL)[i]; s = ((const float*)WcSD)[i]; }
        else     { g = __bfloat162float(((const bf16*)WcGL)[i]);
                   s = __bfloat162float(((const bf16*)WcSD)[i]); }
        ws[P_WTGL + (size_t)r * 64 + ft] = g;
        ws[P_WTSD + (size_t)r * 64 + ft] = s;
    }
}

// -------- t_lhs[b,t,j] = (sum_v x*U1) @ U2 ; one block per (b,t) --------
__global__ void k_tlhs(float* ws) {
    __shared__ float sh[V * F];
    __shared__ float xu[F];
    int blk = blockIdx.x; int b = blk / T, t = blk - b * T;
    int tid = threadIdx.x;
    if (tid < V) {
        float u1v = ws[P_U1 + tid];
        const float* xr = ws + XF + ((size_t)b * T + t) * VF + tid * F;
        #pragma unroll
        for (int f = 0; f < F; f++) sh[tid * F + f] = xr[f] * u1v;
    }
    __syncthreads();
    if (tid < F) {
        float s = 0;
        for (int v = 0; v < V; v++) s += sh[v * F + tid];
        xu[tid] = s;
    }
    __syncthreads();
    if (tid < V) {
        float acc = 0;
        #pragma unroll
        for (int f = 0; f < F; f++) acc += xu[f] * ws[P_U2 + f * V + tid];
        ws[TLHS + ((size_t)b * T + t) * V + tid] = acc;
    }
}

// -------- t_rhs[b,v,t] = sum_f x[b,t,v,f]*U3[f] --------
__global__ void k_trhs(float* ws) {
    int i0 = blockIdx.x * blockDim.x + threadIdx.x;
    int st = gridDim.x * blockDim.x;
    for (int idx = i0; idx < B * V * T; idx += st) {
        int b = idx / (V * T); int r = idx - b * V * T; int v = r / T; int t = r - v * T;
        const float* xr = ws + XF + ((size_t)b * T + t) * VF + v * F;
        float acc = 0;
        #pragma unroll
        for (int f = 0; f < F; f++) acc += xr[f] * ws[P_U3 + f];
        ws[TRHS + idx] = acc;
    }
}

// -------- prod[b,i,k] = sum_j tlhs[b,i,j]*trhs[b,j,k] ; block per (b,i) --------
// tlhs row staged in LDS: the per-j reads are wave-uniform (broadcast-load trap).
__global__ __launch_bounds__(256) void k_prod(float* ws) {
    __shared__ float ls[V];
    int blk = blockIdx.x; int b = blk / T, i = blk - b * T;
    int k = threadIdx.x;
    int k2 = min(k + 256, T - 1); bool w2 = (k + 256) < T;
    const float* lr = ws + TLHS + ((size_t)b * T + i) * V;
    const float* rr = ws + TRHS + (size_t)b * V * T;
    if (k < V) ls[k] = lr[k];
    __syncthreads();
    float a0 = 0, a1 = 0;
    for (int j = 0; j < V; j++) {
        float l = ls[j];
        a0 += l * rr[(size_t)j * T + k];
        a1 += l * rr[(size_t)j * T + k2];
    }
    float* o = ws + PRODT + (size_t)b * TT + (size_t)i * T;
    o[k] = a0;
    if (w2) o[k2] = a1;
}

// -------- Sraw = sigmoid(V_e @ prod + b_e), 4 rows per block --------
// V_e rows staged in LDS (were wave-uniform broadcast global loads).
constexpr int IG = 4, NIG = (T + IG - 1) / IG; // 67
__global__ __launch_bounds__(256) void k_sraw(float* ws) {
    __shared__ float ve[IG * T];    // 4 rows x 265 = 4.2 KB
    int blk = blockIdx.x; int b = blk / NIG; int i0 = (blk - b * NIG) * IG;
    int k = threadIdx.x;
    int k2 = min(k + 256, T - 1); bool w2 = (k + 256) < T;
    const float* pr = ws + PRODT + (size_t)b * TT;
    for (int i = k; i < IG * T; i += 256) {
        int q = i / T, j = i - q * T;
        int ii = min(i0 + q, T - 1);
        ve[i] = ws[P_VE + (size_t)ii * T + j];
    }
    __syncthreads();
    float a0[IG] = {0, 0, 0, 0}, a1[IG] = {0, 0, 0, 0};
    for (int j = 0; j < T; j++) {
        const float* row = pr + (size_t)j * T;
        float r0 = row[k], r1 = row[k2];
        #pragma unroll
        for (int q = 0; q < IG; q++) {
            float v = ve[q * T + j];
            a0[q] += v * r0; a1[q] += v * r1;
        }
    }
    #pragma unroll
    for (int q = 0; q < IG; q++) {
        int i = i0 + q;
        if (i < T) {
            float* o = ws + SRAWT + (size_t)b * TT + (size_t)i * T;
            o[k] = sigmoidf_(a0[q] + ws[P_BE + (size_t)i * T + k]);
            if (w2) o[k2] = sigmoidf_(a1[q] + ws[P_BE + (size_t)i * T + k2]);
        }
    }
}

// -------- column softmax, tiled & coalesced: block per (b, 64-wide k tile) --------
constexpr int KTI = (T + 63) / 64;  // 5
__global__ __launch_bounds__(256) void k_tsm(float* ws) {
    __shared__ float red[4][64];
    __shared__ float cstat[64];
    int blk = blockIdx.x; int b = blk / KTI; int k0 = (blk - b * KTI) * 64;
    int ks = threadIdx.x & 63; int isub = threadIdx.x >> 6;
    int k = k0 + ks; bool act = k < T;
    float* S = ws + SRAWT + (size_t)b * TT;
    float m = -1e30f;
    if (act) for (int i = isub; i < T; i += 4) m = fmaxf(m, S[(size_t)i * T + k]);
    red[isub][ks] = m;
    __syncthreads();
    if (isub == 0)
        cstat[ks] = fmaxf(fmaxf(red[0][ks], red[1][ks]), fmaxf(red[2][ks], red[3][ks]));
    __syncthreads();
    m = cstat[ks];
    float s = 0;
    if (act) for (int i = isub; i < T; i += 4) s += expf(S[(size_t)i * T + k] - m);
    __syncthreads();
    red[isub][ks] = s;
    __syncthreads();
    if (isub == 0)
        cstat[ks] = 1.f / (red[0][ks] + red[1][ks] + red[2][ks] + red[3][ks]);
    __syncthreads();
    float inv = cstat[ks];
    if (act) for (int i = isub; i < T; i += 4) {
        size_t o = (size_t)i * T + k;
        S[o] = expf(S[o] - m) * inv;
    }
}

// -------- y[b,p,t] = sum_s x_flat[b,p,s]*TAtt[b,s,t]; 8 p per block --------
constexpr int PG = 8, NPG = (VF + PG - 1) / PG; // 39
__global__ __launch_bounds__(256) void k_y(float* ws) {
    __shared__ float xs[T * PG];    // 265 x 8 = 8.3 KB
    int blk = blockIdx.x; int b = blk / NPG; int p0 = (blk - b * NPG) * PG;
    int t = threadIdx.x;
    int t2 = min(t + 256, T - 1); bool w2 = (t + 256) < T;
    const float* xb = ws + XF + (size_t)b * TVF;
    const float* ta = ws + SRAWT + (size_t)b * TT;
    for (int i = threadIdx.x; i < T * PG; i += 256) {
        int s = i >> 3, j = i & 7;   // tail lanes read past x into TLHS: finite, unused
        xs[i] = xb[(size_t)s * VF + p0 + j];
    }
    __syncthreads();
    float a0[PG], a1[PG];
    #pragma unroll
    for (int j = 0; j < PG; j++) { a0[j] = 0; a1[j] = 0; }
    for (int s = 0; s < T; s++) {
        float ta0 = ta[(size_t)s * T + t];
        float ta1 = ta[(size_t)s * T + t2];
        const float* xr = xs + s * PG;
        #pragma unroll
        for (int j = 0; j < PG; j++) {  // broadcast LDS reads (free)
            float xv = xr[j];
            a0[j] += xv * ta0; a1[j] += xv * ta1;
        }
    }
    float* yb = ws + YBUF + (size_t)b * VF * T;
    #pragma unroll
    for (int j = 0; j < PG; j++) {
        if (p0 + j < VF) {
            yb[(size_t)(p0 + j) * T + t] = a0[j];
            if (w2) yb[(size_t)(p0 + j) * T + t2] = a1[j];
        }
    }
}

// -------- xw[b,v,f] = sum_t x_TAtt[b,t,v,f]*W1[t]; block per (b, 64-wide p tile) --------
constexpr int PTI = (VF + 63) / 64;  // 5
__global__ __launch_bounds__(256) void k_xw(float* ws) {
    __shared__ float red[4][64];
    __shared__ float w1s[T];
    int blk = blockIdx.x; int b = blk / PTI; int p0 = (blk - b * PTI) * 64;
    int ps = threadIdx.x & 63; int tsub = threadIdx.x >> 6;
    int p = p0 + ps; bool act = p < VF;
    for (int i = threadIdx.x; i < T; i += 256) w1s[i] = ws[P_W1 + i];
    const float* yb = ws + YBUF + (size_t)b * TVF;
    __syncthreads();
    float acc = 0;
    if (act) for (int t = tsub; t < T; t += 4) acc += yb[(size_t)t * VF + p] * w1s[t];
    red[tsub][ps] = acc;
    __syncthreads();
    if (tsub == 0 && act)
        ws[XWOF + (size_t)b * VF + p] = red[0][ps] + red[1][ps] + red[2][ps] + red[3][ps];
}

// -------- merged s_lhs + s_rhs --------
__global__ void k_ssr(float* ws) {
    int i0 = blockIdx.x * blockDim.x + threadIdx.x;
    int st = gridDim.x * blockDim.x;
    for (int idx = i0; idx < B * V * T; idx += st) {   // s_lhs[b,v,j]
        int b = idx / (V * T); int r = idx - b * V * T; int v = r / T; int j = r - v * T;
        float acc = 0;
        #pragma unroll
        for (int f = 0; f < F; f++)
            acc += ws[XWOF + (size_t)b * VF + v * F + f] * ws[P_W2 + (size_t)f * T + j];
        ws[SLHS + idx] = acc;
    }
    for (int idx = i0; idx < B * T * V; idx += st) {   // s_rhs[b,t,v]
        int b = idx / (T * V); int r = idx - b * T * V; int t = r / V; int v = r - t * V;
        const float* yr = ws + YBUF + (size_t)b * TVF + (size_t)t * VF + v * F;
        float acc = 0;
        #pragma unroll
        for (int f = 0; f < F; f++) acc += yr[f] * ws[P_W3 + f];
        ws[SRHS + idx] = acc;
    }
}

// -------- sp[b,i,k] = sum_j slhs[b,i,j]*srhs[b,j,k] (grid-stride, coalesced) --------
__global__ void k_sprod(float* ws) {
    int i0 = blockIdx.x * blockDim.x + threadIdx.x;
    int st = gridDim.x * blockDim.x;
    for (int idx = i0; idx < B * VV; idx += st) {
        int b = idx / VV; int r = idx - b * VV; int i = r / V; int k = r - i * V;
        const float* sl = ws + SLHS + (size_t)b * V * T + (size_t)i * T;
        const float* sr = ws + SRHS + (size_t)b * T * V;
        float acc = 0;
        for (int j = 0; j < T; j++) acc += sl[j] * sr[(size_t)j * V + k];
        ws[SPROD + idx] = acc;
    }
}

// -------- SAtt = colsoftmax(sigmoid(Vs@sp + bs)) ; block per b (small) --------
__global__ __launch_bounds__(256) void k_satt(float* ws) {
    __shared__ float sp[VV];
    __shared__ float s2[VV];
    int b = blockIdx.x, tid = threadIdx.x;
    for (int i = tid; i < VV; i += 256) sp[i] = ws[SPROD + (size_t)b * VV + i];
    __syncthreads();
    for (int idx = tid; idx < VV; idx += 256) {
        int i = idx / V, k = idx - i * V;
        float acc = 0;
        for (int j = 0; j < V; j++) acc += ws[P_VS + (size_t)i * V + j] * sp[j * V + k];
        s2[idx] = sigmoidf_(acc + ws[P_BS + idx]);
    }
    __syncthreads();
    if (tid < V) {
        int k = tid;
        float m = -1e30f;
        for (int i = 0; i < V; i++) m = fmaxf(m, s2[i * V + k]);
        float sum = 0;
        for (int i = 0; i < V; i++) sum += expf(s2[i * V + k] - m);
        float inv = 1.f / sum;
        for (int i = 0; i < V; i++)
            ws[SATT + (size_t)b * VV + i * V + k] = expf(s2[i * V + k] - m) * inv;
    }
}

// -------- per-(b,t) fused graph-learning + Chebyshev convs into ring --------
__global__ __launch_bounds__(256) void k_cheb(float* ws, int t0) {
    __shared__ float xt[VF];
    __shared__ float sa[VV];
    __shared__ float bufA[VV];   // Sg -> T2 -> M2 -> (sel1 Mk)
    __shared__ float bufB[VV];   // A -> L -> M1
    __shared__ float rhs[VF];
    __shared__ float z[V * FC];
    __shared__ float rsum[64];
    __shared__ float ag[8];
    int blk = blockIdx.x; int b = blk / RS, slot = blk - b * RS;
    int t = t0 - 1 + slot;
    if (t < 0 || t >= T) return;               // block-uniform
    int tid = threadIdx.x;
    for (int i = tid; i < VF; i += 256) xt[i] = ws[XF + (size_t)b * TVF + (size_t)t * VF + i];
    if (tid < F) ag[tid] = ws[P_AGL + tid];
    for (int i = tid; i < VV; i += 256) sa[i] = ws[SATT + (size_t)b * VV + i];
    __syncthreads();
    for (int idx = tid; idx < VV; idx += 256) {   // Sg = exp(|xu-xv|.a)
        int u = idx / V, v = idx - u * V;
        float acc = 0;
        #pragma unroll
        for (int f = 0; f < F; f++) acc += fabsf(xt[u * F + f] - xt[v * F + f]) * ag[f];
        bufA[idx] = expf(acc);
    }
    __syncthreads();
    if (tid < V) { float s = 0; for (int v = 0; v < V; v++) s += bufA[tid * V + v]; rsum[tid] = s; }
    __syncthreads();
    for (int idx = tid; idx < VV; idx += 256) {   // A = min(Sgn, Sgn^T)
        int u = idx / V, v = idx - u * V;
        float a = bufA[u * V + v] / rsum[u];
        float s = bufA[v * V + u] / rsum[v];
        bufB[idx] = fminf(a, s);
    }
    __syncthreads();
    if (tid < V) { float s = 0; for (int v = 0; v < V; v++) s += bufB[tid * V + v]; rsum[tid] = s; }
    __syncthreads();
    for (int idx = tid; idx < VV; idx += 256) {   // L = diag(d-1) - A
        int u = idx / V, v = idx - u * V;
        bufB[idx] = ((u == v) ? (rsum[u] - 1.f) : 0.f) - bufB[idx];
    }
    __syncthreads();
    {   // T2 = 2 L@L - I, register-tiled 4x4 (2 MAC per LDS read)
        int tu = tid >> 4, tv = tid & 15;
        float acc4[4][4];
        #pragma unroll
        for (int a = 0; a < 4; a++)
            #pragma unroll
            for (int c = 0; c < 4; c++) acc4[a][c] = 0.f;
        for (int k = 0; k < V; k++) {
            float av[4], bv[4];
            #pragma unroll
            for (int d = 0; d < 4; d++) {
                int u = 4 * tu + d;
                av[d] = (u < V) ? bufB[u * V + k] : 0.f;
                int v = 4 * tv + d;
                bv[d] = (v < V) ? bufB[k * V + v] : 0.f;
            }
            #pragma unroll
            for (int a = 0; a < 4; a++)
                #pragma unroll
                for (int c = 0; c < 4; c++) acc4[a][c] += av[a] * bv[c];
        }
        __syncthreads();
        #pragma unroll
        for (int a = 0; a < 4; a++) {
            int u = 4 * tu + a;
            if (u >= V) continue;
            #pragma unroll
            for (int c = 0; c < 4; c++) {
                int v = 4 * tv + c;
                if (v >= V) continue;
                bufA[u * V + v] = 2.f * acc4[a][c] - ((u == v) ? 1.f : 0.f);
            }
        }
    }
    __syncthreads();
    for (int idx = tid; idx < VV; idx += 256) {   // M1 = L.SA, M2 = T2.SA (elementwise)
        float s = sa[idx];
        bufB[idx] *= s;
        bufA[idx] *= s;
    }
    __syncthreads();
    for (int sel = 0; sel < 2; sel++) {
        for (int i = tid; i < V * FC; i += 256) z[i] = 0;
        __syncthreads();
        const float* Th = ws + (sel ? P_THSD : P_THGL);
        for (int kk = 0; kk < Kc; kk++) {
            if (sel == 1 && kk > 0) {   // stage Mk = C_kk . SA into bufA
                const float* C = ws + P_CHEB + (size_t)kk * VV;
                for (int idx = tid; idx < VV; idx += 256) bufA[idx] = C[idx] * sa[idx];
                __syncthreads();
            }
            for (int idx = tid; idx < VF; idx += 256) {  // rhs[u,f] = sum_v M[v,u]*x[v,f]
                int u = idx / F, f = idx - u * F;
                float acc = 0;
                if (kk == 0) {
                    acc = sa[u * V + u] * xt[u * F + f];   // T0 = I (both GL and SD)
                } else {
                    const float* M = (sel == 0 && kk == 1) ? bufB : bufA;
                    for (int v = 0; v < V; v++) acc += M[v * V + u] * xt[v * F + f];
                }
                rhs[idx] = acc;
            }
            __syncthreads();
            for (int idx = tid; idx < V * FC; idx += 256) {
                int u = idx / FC, o = idx - u * FC;
                float acc = 0;
                #pragma unroll
                for (int f = 0; f < F; f++) acc += rhs[u * F + f] * Th[(kk * F + f) * FC + o];
                z[idx] += acc;
            }
            __syncthreads();
        }
        float* outp = ws + RING + (((size_t)sel * B + b) * RS + slot) * V * FC;
        for (int idx = tid; idx < V * FC; idx += 256) outp[idx] = fmaxf(z[idx], 0.f);
        __syncthreads();
    }
}

// -------- conv(3x1) + bias + layernorm(FT) + store; block per (sel, b, t-pair) --------
// Register-tiled GEMM: out[ft][v] = sum_{k=(c,kt)} W[k][ft] * R[k][v].
// Thread (tf,tv) owns a 4ft x 4v tile. Ring staged TRANSPOSED [slot][c][v] so the
// R-operand read is one lane-DISTINCT ds_read_b128 (256B useful/instr) instead of
// the previous wave-uniform broadcast reads (16B/instr) that made k_conv
// LDS-instruction-bound (4 FMA/read -> now 16 FMA/read, conflict-free).
constexpr int TG = 2, NTG = CH / TG;  // 2 t per block, 16 groups per chunk
constexpr int RST = 68;               // transposed slot stride: 16B-aligned, 2-way-read banks
__global__ __launch_bounds__(256, 2) void k_conv(const float* ws, void* outv, int t0) {
    __shared__ float ring_s[(TG + 2) * 64 * RST];   // [slot][c][v+pad] = 68 KiB
    __shared__ float red_s[2][16][64];              // LN partials over ft-groups (8 KiB)
    __shared__ float mus[64], rsg[64];
    int blk = blockIdx.x;
    int sel = (blk >= B * NTG) ? 1 : 0;
    int r0  = blk - sel * B * NTG;
    int b = r0 / NTG, tg = r0 - b * NTG;
    int tbase = t0 + tg * TG;
    if (tbase >= T) return;                       // block-uniform
    int tid = threadIdx.x;
    int tv = tid & 15, tf = tid >> 4;             // v-quad, ft-quad
    bool isf = ws[FLAG] != 0.f;
    const float* wt = ws + (sel ? P_WTSD : P_WTGL);   // [fc*3+kt][ft] (global, L2-hot)
    const float* ringb = ws + RING + ((size_t)sel * B + b) * RS * V * FC
                       + (size_t)(tg * TG) * V * FC;
    // zero the pad columns (v=62..67) so main loop needs no v-bounds checks
    for (int i = tid; i < (TG + 2) * 64 * (RST - V); i += 256) {
        int sc = i / (RST - V), p = i - sc * (RST - V);
        ring_s[sc * RST + V + p] = 0.f;
    }
    // stage 4 slots, transposed [v][c]->[c][v]; invalid halo slots zeroed
    for (int i = tid; i < (TG + 2) * V * FC; i += 256) {
        int s = i / (V * FC), e = i - s * (V * FC);
        int v = e >> 6, c = e & 63;
        int tglob = tbase - 1 + s;
        float val = (tglob >= 0 && tglob < T) ? ringb[i] : 0.f;
        ring_s[(s * 64 + c) * RST + v] = val;
    }
    float bc[4], gg[4], bb[4];
    #pragma unroll
    for (int a = 0; a < 4; a++) {
        bc[a] = ws[(sel ? P_BCSD : P_BCGL) + 4 * tf + a];
        gg[a] = ws[(sel ? P_GSD  : P_GGL)  + 4 * tf + a];
        bb[a] = ws[(sel ? P_BESD : P_BEGL) + 4 * tf + a];
    }
    __syncthreads();
    float acc[TG][16];
    #pragma unroll
    for (int j = 0; j < TG; j++)
        #pragma unroll
        for (int i = 0; i < 16; i++) acc[j][i] = 0.f;

    // main GEMM loop over k=(c,kt), c in chunks of 4, W double-buffered (A/B)
    float4 wvA[12], wvB[12];
    #pragma unroll
    for (int q = 0; q < 4; q++)
        #pragma unroll
        for (int kt = 0; kt < 3; kt++)
            wvA[q * 3 + kt] = *(const float4*)&wt[((0 + q) * 3 + kt) * 64 + 4 * tf];
    #pragma unroll
    for (int cc2 = 0; cc2 < 8; cc2++) {
        int ccA = 2 * cc2, ccB = 2 * cc2 + 1;
        #pragma unroll
        for (int q = 0; q < 4; q++)
            #pragma unroll
            for (int kt = 0; kt < 3; kt++)
                wvB[q * 3 + kt] = *(const float4*)&wt[((ccB * 4 + q) * 3 + kt) * 64 + 4 * tf];
        #pragma unroll
        for (int j = 0; j < TG; j++)
            #pragma unroll
            for (int kt = 0; kt < 3; kt++)
                #pragma unroll
                for (int q = 0; q < 4; q++) {
                    float4 rv = *(const float4*)&ring_s[(((j + kt) << 6) + ccA * 4 + q) * RST + 4 * tv];
                    const float* wp = (const float*)&wvA[q * 3 + kt];
                    const float* rp = (const float*)&rv;
                    #pragma unroll
                    for (int a = 0; a < 4; a++)
                        #pragma unroll
                        for (int d = 0; d < 4; d++)
                            acc[j][a * 4 + d] += wp[a] * rp[d];
                }
        if (cc2 < 7) {
            int ccN = 2 * cc2 + 2;
            #pragma unroll
            for (int q = 0; q < 4; q++)
                #pragma unroll
                for (int kt = 0; kt < 3; kt++)
                    wvA[q * 3 + kt] = *(const float4*)&wt[((ccN * 4 + q) * 3 + kt) * 64 + 4 * tf];
        }
        #pragma unroll
        for (int j = 0; j < TG; j++)
            #pragma unroll
            for (int kt = 0; kt < 3; kt++)
                #pragma unroll
                for (int q = 0; q < 4; q++) {
                    float4 rv = *(const float4*)&ring_s[(((j + kt) << 6) + ccB * 4 + q) * RST + 4 * tv];
                    const float* wp = (const float*)&wvB[q * 3 + kt];
                    const float* rp = (const float*)&rv;
                    #pragma unroll
                    for (int a = 0; a < 4; a++)
                        #pragma unroll
                        for (int d = 0; d < 4; d++)
                            acc[j][a * 4 + d] += wp[a] * rp[d];
                }
    }

    // epilogue: per-t layernorm over ft (LDS tree across tf-groups) + direct store
    #pragma unroll
    for (int j = 0; j < TG; j++) {
        int t = tbase + j;
        if (t >= T) break;                        // block-uniform
        float ps[4], pq[4];
        #pragma unroll
        for (int d = 0; d < 4; d++) { ps[d] = 0.f; pq[d] = 0.f; }
        #pragma unroll
        for (int a = 0; a < 4; a++)
            #pragma unroll
            for (int d = 0; d < 4; d++) {
                float v = acc[j][a * 4 + d] + bc[a];
                ps[d] += v; pq[d] += v * v;
            }
        #pragma unroll
        for (int d = 0; d < 4; d++) {
            red_s[0][tf][4 * tv + d] = ps[d];
            red_s[1][tf][4 * tv + d] = pq[d];
        }
        __syncthreads();
        if (tid < 64) {
            float s = 0.f, q = 0.f;
            #pragma unroll
            for (int g = 0; g < 16; g++) { s += red_s[0][g][tid]; q += red_s[1][g][tid]; }
            float mu  = s * (1.f / 64.f);
            float var = q * (1.f / 64.f) - mu * mu;
            mus[tid] = mu; rsg[tid] = rsqrtf(var + 1e-5f);
        }
        __syncthreads();
        size_t obase = (size_t)sel * B * FT * T * V;
        #pragma unroll
        for (int a = 0; a < 4; a++) {
            int ft = 4 * tf + a;
            size_t orow = obase + (((size_t)(b * FT + ft)) * T + t) * V;
            #pragma unroll
            for (int d = 0; d < 4; d++) {
                int v = 4 * tv + d;
                if (v < V) {
                    float val = (acc[j][a * 4 + d] + bc[a] - mus[v]) * rsg[v] * gg[a] + bb[a];
                    if (isf) ((float*)outv)[orow + v] = val;
                    else     ((bf16*)outv)[orow + v] = __float2bfloat16(val);
                }
            }
        }
    }
}

extern "C" void kernel_launch(void* const* d_in, const int* in_sizes, int n_in,
                              void* d_out, int out_size, void* d_ws, size_t ws_size,
                              hipStream_t stream) {
    float* ws = (float*)d_ws;
    hipLaunchKernelGGL(k_dtype, dim3(1), dim3(256), 0, stream, d_in[0], ws);
    hipLaunchKernelGGL(k_prep, dim3(256), dim3(256), 0, stream,
                       d_in[0], d_in[1], d_in[2], d_in[3], d_in[4], d_in[5], d_in[6],
                       d_in[7], d_in[8], d_in[9], d_in[10], d_in[11], d_in[12], d_in[13],
                       d_in[14], d_in[15], d_in[16], d_in[17], d_in[18], d_in[19],
                       d_in[20], d_in[21], d_in[22], ws);
    hipLaunchKernelGGL(k_tlhs,  dim3(BT),        dim3(64),  0, stream, ws);
    hipLaunchKernelGGL(k_trhs,  dim3(512),       dim3(256), 0, stream, ws);
    hipLaunchKernelGGL(k_prod,  dim3(BT),        dim3(256), 0, stream, ws);
    hipLaunchKernelGGL(k_sraw,  dim3(B * NIG),   dim3(256), 0, stream, ws);
    hipLaunchKernelGGL(k_tsm,   dim3(B * KTI),   dim3(256), 0, stream, ws);
    hipLaunchKernelGGL(k_y,     dim3(B * NPG),   dim3(256), 0, stream, ws);
    hipLaunchKernelGGL(k_xw,    dim3(B * PTI),   dim3(256), 0, stream, ws);
    hipLaunchKernelGGL(k_ssr,   dim3(512),       dim3(256), 0, stream, ws);
    hipLaunchKernelGGL(k_sprod, dim3(241),       dim3(256), 0, stream, ws);
    hipLaunchKernelGGL(k_satt,  dim3(B),         dim3(256), 0, stream, ws);
    for (int ci = 0; ci < NCHK; ci++) {
        int t0 = ci * CH;
        hipLaunchKernelGGL(k_cheb, dim3(B * RS),       dim3(256), 0, stream, ws, t0);
        hipLaunchKernelGGL(k_conv, dim3(B * NTG * 2),  dim3(256), 0, stream, ws, d_out, t0);
    }
}

// Round 5
// 1540.375 us; speedup vs baseline: 2.7784x; 2.7784x over previous
//
#include <hip/hip_runtime.h>
#include <hip/hip_bf16.h>
#include <math.h>

typedef __hip_bfloat16 bf16;

constexpr int B = 16, T = 265, V = 62, F = 5, Kc = 3, FC = 64, FT = 64, KT = 3;
constexpr int VF  = V * F;      // 310
constexpr int VV  = V * V;      // 3844
constexpr int TT  = T * T;      // 70225
constexpr int TVF = T * V * F;  // 82150
constexpr int BT  = B * T;      // 4240
constexpr int CH  = 32;         // t-chunk size
constexpr int RS  = CH + 2;     // ring slots (halo 1 each side)
constexpr int NCHK = (T + CH - 1) / CH;  // 9

// ---------------- workspace layout (float offsets), params first ----------------
constexpr size_t FLAG  = 0;                          // dtype flag (0=bf16,1=f32)
constexpr size_t P_U1  = 4;
constexpr size_t P_U2  = P_U1 + 62;
constexpr size_t P_U3  = P_U2 + 310;
constexpr size_t P_BE  = P_U3 + 5;
constexpr size_t P_VE  = P_BE + 70225;
constexpr size_t P_W1  = P_VE + 70225;
constexpr size_t P_W2  = P_W1 + 265;
constexpr size_t P_W3  = P_W2 + 1325;
constexpr size_t P_BS  = P_W3 + 5;
constexpr size_t P_VS  = P_BS + 3844;
constexpr size_t P_AGL = P_VS + 3844;
constexpr size_t P_THGL= P_AGL + 5;
constexpr size_t P_THSD= P_THGL + 960;
constexpr size_t P_CHEB= P_THSD + 960;               // (K,V,V)
constexpr size_t P_WTGL= P_CHEB + 11532;             // transposed [fc*3+kt][ft]
constexpr size_t P_BCGL= P_WTGL + 12288;
constexpr size_t P_WTSD= P_BCGL + 64;
constexpr size_t P_BCSD= P_WTSD + 12288;
constexpr size_t P_GGL = P_BCSD + 64;
constexpr size_t P_BEGL= P_GGL + 64;
constexpr size_t P_GSD = P_BEGL + 64;
constexpr size_t P_BESD= P_GSD + 64;
constexpr size_t PEND  = (P_BESD + 64 + 3) & ~(size_t)3;
// working buffers
constexpr size_t XF    = PEND;                       // (B,T,V,F) fp32 x
constexpr size_t TLHS  = XF    + (size_t)B*T*V*F;    // (B,T,V)
constexpr size_t TRHS  = TLHS  + (size_t)B*T*V;      // (B,V,T)
constexpr size_t PRODT = TRHS  + (size_t)B*V*T;      // (B,T,T)
constexpr size_t SRAWT = PRODT + (size_t)B*TT;       // (B,T,T) -> TAtt in place
constexpr size_t YBUF  = SRAWT + (size_t)B*TT;       // (B,VF,T) == x_TAtt (B,T,V,F)
constexpr size_t XWOF  = YBUF  + (size_t)B*VF*T;     // (B,V,F)
constexpr size_t SLHS  = XWOF  + (size_t)B*V*F;      // (B,V,T)
constexpr size_t SRHS  = SLHS  + (size_t)B*V*T;      // (B,T,V)
constexpr size_t SATT  = SRHS  + (size_t)B*T*V;      // (B,V,V)
constexpr size_t SPROD = PRODT;                      // alias: PRODT dead after k_sraw
constexpr size_t RING  = SATT  + (size_t)B*V*V;      // (2,B,RS,V,FC)

static __device__ __forceinline__ float sigmoidf_(float x) {
    return 1.f / (1.f + expf(-x));
}

// -------- dtype probe: are inputs bf16 or f32? --------
__global__ void k_dtype(const void* x, float* ws) {
    __shared__ int cnt;
    if (threadIdx.x == 0) cnt = 0;
    __syncthreads();
    int bad = 0;
    const bf16* p = (const bf16*)x;
    for (int i = threadIdx.x; i < 4096; i += 256) {
        float v = __bfloat162float(p[i]);
        if (!isfinite(v) || fabsf(v) > 1e3f || (v != 0.f && fabsf(v) < 1e-10f)) bad++;
    }
    atomicAdd(&cnt, bad);
    __syncthreads();
    if (threadIdx.x == 0) ws[FLAG] = (cnt > 100) ? 1.f : 0.f;
}

static __device__ __forceinline__ void cvtany(const void* s, float* d, int n,
                                              int tid, int st, bool isf) {
    if (isf) {
        const float* p = (const float*)s;
        for (int i = tid; i < n; i += st) d[i] = p[i];
    } else {
        const bf16* p = (const bf16*)s;
        for (int i = tid; i < n; i += st) d[i] = __bfloat162float(p[i]);
    }
}

// -------- convert all inputs to fp32 workspace (Wc transposed) --------
__global__ void k_prep(const void* x, const void* U1, const void* U2, const void* U3,
                       const void* bE, const void* Ve, const void* W1, const void* W2,
                       const void* W3, const void* bS, const void* Vs, const void* aGL,
                       const void* ThGL, const void* ThSD, const void* Cheb,
                       const void* WcGL, const void* bcGL, const void* WcSD, const void* bcSD,
                       const void* gGL, const void* beGL, const void* gSD, const void* beSD,
                       float* ws) {
    int tid = blockIdx.x * blockDim.x + threadIdx.x;
    int st  = gridDim.x * blockDim.x;
    bool isf = ws[FLAG] != 0.f;
    cvtany(x,    ws + XF,    B*T*V*F, tid, st, isf);
    cvtany(U1,   ws + P_U1,  62,    tid, st, isf);
    cvtany(U2,   ws + P_U2,  310,   tid, st, isf);
    cvtany(U3,   ws + P_U3,  5,     tid, st, isf);
    cvtany(bE,   ws + P_BE,  70225, tid, st, isf);
    cvtany(Ve,   ws + P_VE,  70225, tid, st, isf);
    cvtany(W1,   ws + P_W1,  265,   tid, st, isf);
    cvtany(W2,   ws + P_W2,  1325,  tid, st, isf);
    cvtany(W3,   ws + P_W3,  5,     tid, st, isf);
    cvtany(bS,   ws + P_BS,  3844,  tid, st, isf);
    cvtany(Vs,   ws + P_VS,  3844,  tid, st, isf);
    cvtany(aGL,  ws + P_AGL, 5,     tid, st, isf);
    cvtany(ThGL, ws + P_THGL, 960,  tid, st, isf);
    cvtany(ThSD, ws + P_THSD, 960,  tid, st, isf);
    cvtany(Cheb, ws + P_CHEB, 11532, tid, st, isf);
    cvtany(bcGL, ws + P_BCGL, 64, tid, st, isf);
    cvtany(bcSD, ws + P_BCSD, 64, tid, st, isf);
    cvtany(gGL,  ws + P_GGL,  64, tid, st, isf);
    cvtany(beGL, ws + P_BEGL, 64, tid, st, isf);
    cvtany(gSD,  ws + P_GSD,  64, tid, st, isf);
    cvtany(beSD, ws + P_BESD, 64, tid, st, isf);
    // Wc (FT,FC,KT,1) -> [fc*3+kt][ft]
    for (int i = tid; i < 12288; i += st) {
        int ft = i / 192, r = i - ft * 192;
        float g, s;
        if (isf) { g = ((const float*)WcGL)[i]; s = ((const float*)WcSD)[i]; }
        else     { g = __bfloat162float(((const bf16*)WcGL)[i]);
                   s = __bfloat162float(((const bf16*)WcSD)[i]); }
        ws[P_WTGL + (size_t)r * 64 + ft] = g;
        ws[P_WTSD + (size_t)r * 64 + ft] = s;
    }
}

// -------- t_lhs[b,t,j] = (sum_v x*U1) @ U2 ; one block per (b,t) --------
__global__ void k_tlhs(float* ws) {
    __shared__ float sh[V * F];
    __shared__ float xu[F];
    int blk = blockIdx.x; int b = blk / T, t = blk - b * T;
    int tid = threadIdx.x;
    if (tid < V) {
        float u1v = ws[P_U1 + tid];
        const float* xr = ws + XF + ((size_t)b * T + t) * VF + tid * F;
        #pragma unroll
        for (int f = 0; f < F; f++) sh[tid * F + f] = xr[f] * u1v;
    }
    __syncthreads();
    if (tid < F) {
        float s = 0;
        for (int v = 0; v < V; v++) s += sh[v * F + tid];
        xu[tid] = s;
    }
    __syncthreads();
    if (tid < V) {
        float acc = 0;
        #pragma unroll
        for (int f = 0; f < F; f++) acc += xu[f] * ws[P_U2 + f * V + tid];
        ws[TLHS + ((size_t)b * T + t) * V + tid] = acc;
    }
}

// -------- t_rhs[b,v,t] = sum_f x[b,t,v,f]*U3[f] --------
__global__ void k_trhs(float* ws) {
    int i0 = blockIdx.x * blockDim.x + threadIdx.x;
    int st = gridDim.x * blockDim.x;
    for (int idx = i0; idx < B * V * T; idx += st) {
        int b = idx / (V * T); int r = idx - b * V * T; int v = r / T; int t = r - v * T;
        const float* xr = ws + XF + ((size_t)b * T + t) * VF + v * F;
        float acc = 0;
        #pragma unroll
        for (int f = 0; f < F; f++) acc += xr[f] * ws[P_U3 + f];
        ws[TRHS + idx] = acc;
    }
}

// -------- prod[b,i,k] = sum_j tlhs[b,i,j]*trhs[b,j,k] ; block per (b,i) --------
__global__ __launch_bounds__(256) void k_prod(float* ws) {
    __shared__ float ls[V];
    int blk = blockIdx.x; int b = blk / T, i = blk - b * T;
    int k = threadIdx.x;
    int k2 = min(k + 256, T - 1); bool w2 = (k + 256) < T;
    const float* lr = ws + TLHS + ((size_t)b * T + i) * V;
    const float* rr = ws + TRHS + (size_t)b * V * T;
    if (k < V) ls[k] = lr[k];
    __syncthreads();
    float a0 = 0, a1 = 0;
    for (int j = 0; j < V; j++) {
        float l = ls[j];
        a0 += l * rr[(size_t)j * T + k];
        a1 += l * rr[(size_t)j * T + k2];
    }
    float* o = ws + PRODT + (size_t)b * TT + (size_t)i * T;
    o[k] = a0;
    if (w2) o[k2] = a1;
}

// -------- Sraw = sigmoid(V_e @ prod + b_e), 4 rows per block --------
constexpr int IG = 4, NIG = (T + IG - 1) / IG; // 67
__global__ __launch_bounds__(256) void k_sraw(float* ws) {
    __shared__ float ve[IG * T];    // 4 rows x 265 = 4.2 KB
    int blk = blockIdx.x; int b = blk / NIG; int i0 = (blk - b * NIG) * IG;
    int k = threadIdx.x;
    int k2 = min(k + 256, T - 1); bool w2 = (k + 256) < T;
    const float* pr = ws + PRODT + (size_t)b * TT;
    for (int i = k; i < IG * T; i += 256) {
        int q = i / T, j = i - q * T;
        int ii = min(i0 + q, T - 1);
        ve[i] = ws[P_VE + (size_t)ii * T + j];
    }
    __syncthreads();
    float a0[IG] = {0, 0, 0, 0}, a1[IG] = {0, 0, 0, 0};
    for (int j = 0; j < T; j++) {
        const float* row = pr + (size_t)j * T;
        float r0 = row[k], r1 = row[k2];
        #pragma unroll
        for (int q = 0; q < IG; q++) {
            float v = ve[q * T + j];
            a0[q] += v * r0; a1[q] += v * r1;
        }
    }
    #pragma unroll
    for (int q = 0; q < IG; q++) {
        int i = i0 + q;
        if (i < T) {
            float* o = ws + SRAWT + (size_t)b * TT + (size_t)i * T;
            o[k] = sigmoidf_(a0[q] + ws[P_BE + (size_t)i * T + k]);
            if (w2) o[k2] = sigmoidf_(a1[q] + ws[P_BE + (size_t)i * T + k2]);
        }
    }
}

// -------- column softmax, tiled & coalesced: block per (b, 64-wide k tile) --------
constexpr int KTI = (T + 63) / 64;  // 5
__global__ __launch_bounds__(256) void k_tsm(float* ws) {
    __shared__ float red[4][64];
    __shared__ float cstat[64];
    int blk = blockIdx.x; int b = blk / KTI; int k0 = (blk - b * KTI) * 64;
    int ks = threadIdx.x & 63; int isub = threadIdx.x >> 6;
    int k = k0 + ks; bool act = k < T;
    float* S = ws + SRAWT + (size_t)b * TT;
    float m = -1e30f;
    if (act) for (int i = isub; i < T; i += 4) m = fmaxf(m, S[(size_t)i * T + k]);
    red[isub][ks] = m;
    __syncthreads();
    if (isub == 0)
        cstat[ks] = fmaxf(fmaxf(red[0][ks], red[1][ks]), fmaxf(red[2][ks], red[3][ks]));
    __syncthreads();
    m = cstat[ks];
    float s = 0;
    if (act) for (int i = isub; i < T; i += 4) s += expf(S[(size_t)i * T + k] - m);
    __syncthreads();
    red[isub][ks] = s;
    __syncthreads();
    if (isub == 0)
        cstat[ks] = 1.f / (red[0][ks] + red[1][ks] + red[2][ks] + red[3][ks]);
    __syncthreads();
    float inv = cstat[ks];
    if (act) for (int i = isub; i < T; i += 4) {
        size_t o = (size_t)i * T + k;
        S[o] = expf(S[o] - m) * inv;
    }
}

// -------- y[b,p,t] = sum_s x_flat[b,p,s]*TAtt[b,s,t]; 8 p per block --------
constexpr int PG = 8, NPG = (VF + PG - 1) / PG; // 39
__global__ __launch_bounds__(256) void k_y(float* ws) {
    __shared__ float xs[T * PG];    // 265 x 8 = 8.3 KB
    int blk = blockIdx.x; int b = blk / NPG; int p0 = (blk - b * NPG) * PG;
    int t = threadIdx.x;
    int t2 = min(t + 256, T - 1); bool w2 = (t + 256) < T;
    const float* xb = ws + XF + (size_t)b * TVF;
    const float* ta = ws + SRAWT + (size_t)b * TT;
    for (int i = threadIdx.x; i < T * PG; i += 256) {
        int s = i >> 3, j = i & 7;   // tail lanes read past x into TLHS: finite, unused
        xs[i] = xb[(size_t)s * VF + p0 + j];
    }
    __syncthreads();
    float a0[PG], a1[PG];
    #pragma unroll
    for (int j = 0; j < PG; j++) { a0[j] = 0; a1[j] = 0; }
    for (int s = 0; s < T; s++) {
        float ta0 = ta[(size_t)s * T + t];
        float ta1 = ta[(size_t)s * T + t2];
        const float* xr = xs + s * PG;
        #pragma unroll
        for (int j = 0; j < PG; j++) {  // broadcast LDS reads (free)
            float xv = xr[j];
            a0[j] += xv * ta0; a1[j] += xv * ta1;
        }
    }
    float* yb = ws + YBUF + (size_t)b * VF * T;
    #pragma unroll
    for (int j = 0; j < PG; j++) {
        if (p0 + j < VF) {
            yb[(size_t)(p0 + j) * T + t] = a0[j];
            if (w2) yb[(size_t)(p0 + j) * T + t2] = a1[j];
        }
    }
}

// -------- xw[b,v,f] = sum_t x_TAtt[b,t,v,f]*W1[t]; block per (b, 64-wide p tile) --------
constexpr int PTI = (VF + 63) / 64;  // 5
__global__ __launch_bounds__(256) void k_xw(float* ws) {
    __shared__ float red[4][64];
    __shared__ float w1s[T];
    int blk = blockIdx.x; int b = blk / PTI; int p0 = (blk - b * PTI) * 64;
    int ps = threadIdx.x & 63; int tsub = threadIdx.x >> 6;
    int p = p0 + ps; bool act = p < VF;
    for (int i = threadIdx.x; i < T; i += 256) w1s[i] = ws[P_W1 + i];
    const float* yb = ws + YBUF + (size_t)b * TVF;
    __syncthreads();
    float acc = 0;
    if (act) for (int t = tsub; t < T; t += 4) acc += yb[(size_t)t * VF + p] * w1s[t];
    red[tsub][ps] = acc;
    __syncthreads();
    if (tsub == 0 && act)
        ws[XWOF + (size_t)b * VF + p] = red[0][ps] + red[1][ps] + red[2][ps] + red[3][ps];
}

// -------- merged s_lhs + s_rhs --------
__global__ void k_ssr(float* ws) {
    int i0 = blockIdx.x * blockDim.x + threadIdx.x;
    int st = gridDim.x * blockDim.x;
    for (int idx = i0; idx < B * V * T; idx += st) {   // s_lhs[b,v,j]
        int b = idx / (V * T); int r = idx - b * V * T; int v = r / T; int j = r - v * T;
        float acc = 0;
        #pragma unroll
        for (int f = 0; f < F; f++)
            acc += ws[XWOF + (size_t)b * VF + v * F + f] * ws[P_W2 + (size_t)f * T + j];
        ws[SLHS + idx] = acc;
    }
    for (int idx = i0; idx < B * T * V; idx += st) {   // s_rhs[b,t,v]
        int b = idx / (T * V); int r = idx - b * T * V; int t = r / V; int v = r - t * V;
        const float* yr = ws + YBUF + (size_t)b * TVF + (size_t)t * VF + v * F;
        float acc = 0;
        #pragma unroll
        for (int f = 0; f < F; f++) acc += yr[f] * ws[P_W3 + f];
        ws[SRHS + idx] = acc;
    }
}

// -------- sp[b,i,k] = sum_j slhs[b,i,j]*srhs[b,j,k] (grid-stride, coalesced) --------
__global__ void k_sprod(float* ws) {
    int i0 = blockIdx.x * blockDim.x + threadIdx.x;
    int st = gridDim.x * blockDim.x;
    for (int idx = i0; idx < B * VV; idx += st) {
        int b = idx / VV; int r = idx - b * VV; int i = r / V; int k = r - i * V;
        const float* sl = ws + SLHS + (size_t)b * V * T + (size_t)i * T;
        const float* sr = ws + SRHS + (size_t)b * T * V;
        float acc = 0;
        for (int j = 0; j < T; j++) acc += sl[j] * sr[(size_t)j * V + k];
        ws[SPROD + idx] = acc;
    }
}

// -------- SAtt = colsoftmax(sigmoid(Vs@sp + bs)) ; block per b (small) --------
__global__ __launch_bounds__(256) void k_satt(float* ws) {
    __shared__ float sp[VV];
    __shared__ float s2[VV];
    int b = blockIdx.x, tid = threadIdx.x;
    for (int i = tid; i < VV; i += 256) sp[i] = ws[SPROD + (size_t)b * VV + i];
    __syncthreads();
    for (int idx = tid; idx < VV; idx += 256) {
        int i = idx / V, k = idx - i * V;
        float acc = 0;
        for (int j = 0; j < V; j++) acc += ws[P_VS + (size_t)i * V + j] * sp[j * V + k];
        s2[idx] = sigmoidf_(acc + ws[P_BS + idx]);
    }
    __syncthreads();
    if (tid < V) {
        int k = tid;
        float m = -1e30f;
        for (int i = 0; i < V; i++) m = fmaxf(m, s2[i * V + k]);
        float sum = 0;
        for (int i = 0; i < V; i++) sum += expf(s2[i * V + k] - m);
        float inv = 1.f / sum;
        for (int i = 0; i < V; i++)
            ws[SATT + (size_t)b * VV + i * V + k] = expf(s2[i * V + k] - m) * inv;
    }
}

// -------- per-(b,t) fused graph-learning + Chebyshev convs into ring --------
__global__ __launch_bounds__(256) void k_cheb(float* ws, int t0) {
    __shared__ float xt[VF];
    __shared__ float sa[VV];
    __shared__ float bufA[VV];   // Sg -> T2 -> M2 -> (sel1 Mk)
    __shared__ float bufB[VV];   // A -> L -> M1
    __shared__ float rhs[VF];
    __shared__ float z[V * FC];
    __shared__ float rsum[64];
    __shared__ float ag[8];
    int blk = blockIdx.x; int b = blk / RS, slot = blk - b * RS;
    int t = t0 - 1 + slot;
    if (t < 0 || t >= T) return;               // block-uniform
    int tid = threadIdx.x;
    for (int i = tid; i < VF; i += 256) xt[i] = ws[XF + (size_t)b * TVF + (size_t)t * VF + i];
    if (tid < F) ag[tid] = ws[P_AGL + tid];
    for (int i = tid; i < VV; i += 256) sa[i] = ws[SATT + (size_t)b * VV + i];
    __syncthreads();
    for (int idx = tid; idx < VV; idx += 256) {   // Sg = exp(|xu-xv|.a)
        int u = idx / V, v = idx - u * V;
        float acc = 0;
        #pragma unroll
        for (int f = 0; f < F; f++) acc += fabsf(xt[u * F + f] - xt[v * F + f]) * ag[f];
        bufA[idx] = expf(acc);
    }
    __syncthreads();
    if (tid < V) { float s = 0; for (int v = 0; v < V; v++) s += bufA[tid * V + v]; rsum[tid] = s; }
    __syncthreads();
    for (int idx = tid; idx < VV; idx += 256) {   // A = min(Sgn, Sgn^T)
        int u = idx / V, v = idx - u * V;
        float a = bufA[u * V + v] / rsum[u];
        float s = bufA[v * V + u] / rsum[v];
        bufB[idx] = fminf(a, s);
    }
    __syncthreads();
    if (tid < V) { float s = 0; for (int v = 0; v < V; v++) s += bufB[tid * V + v]; rsum[tid] = s; }
    __syncthreads();
    for (int idx = tid; idx < VV; idx += 256) {   // L = diag(d-1) - A
        int u = idx / V, v = idx - u * V;
        bufB[idx] = ((u == v) ? (rsum[u] - 1.f) : 0.f) - bufB[idx];
    }
    __syncthreads();
    {   // T2 = 2 L@L - I, register-tiled 4x4 (2 MAC per LDS read)
        int tu = tid >> 4, tv = tid & 15;
        float acc4[4][4];
        #pragma unroll
        for (int a = 0; a < 4; a++)
            #pragma unroll
            for (int c = 0; c < 4; c++) acc4[a][c] = 0.f;
        for (int k = 0; k < V; k++) {
            float av[4], bv[4];
            #pragma unroll
            for (int d = 0; d < 4; d++) {
                int u = 4 * tu + d;
                av[d] = (u < V) ? bufB[u * V + k] : 0.f;
                int v = 4 * tv + d;
                bv[d] = (v < V) ? bufB[k * V + v] : 0.f;
            }
            #pragma unroll
            for (int a = 0; a < 4; a++)
                #pragma unroll
                for (int c = 0; c < 4; c++) acc4[a][c] += av[a] * bv[c];
        }
        __syncthreads();
        #pragma unroll
        for (int a = 0; a < 4; a++) {
            int u = 4 * tu + a;
            if (u >= V) continue;
            #pragma unroll
            for (int c = 0; c < 4; c++) {
                int v = 4 * tv + c;
                if (v >= V) continue;
                bufA[u * V + v] = 2.f * acc4[a][c] - ((u == v) ? 1.f : 0.f);
            }
        }
    }
    __syncthreads();
    for (int idx = tid; idx < VV; idx += 256) {   // M1 = L.SA, M2 = T2.SA (elementwise)
        float s = sa[idx];
        bufB[idx] *= s;
        bufA[idx] *= s;
    }
    __syncthreads();
    for (int sel = 0; sel < 2; sel++) {
        for (int i = tid; i < V * FC; i += 256) z[i] = 0;
        __syncthreads();
        const float* Th = ws + (sel ? P_THSD : P_THGL);
        for (int kk = 0; kk < Kc; kk++) {
            if (sel == 1 && kk > 0) {   // stage Mk = C_kk . SA into bufA
                const float* C = ws + P_CHEB + (size_t)kk * VV;
                for (int idx = tid; idx < VV; idx += 256) bufA[idx] = C[idx] * sa[idx];
                __syncthreads();
            }
            for (int idx = tid; idx < VF; idx += 256) {  // rhs[u,f] = sum_v M[v,u]*x[v,f]
                int u = idx / F, f = idx - u * F;
                float acc = 0;
                if (kk == 0) {
                    acc = sa[u * V + u] * xt[u * F + f];   // T0 = I (both GL and SD)
                } else {
                    const float* M = (sel == 0 && kk == 1) ? bufB : bufA;
                    for (int v = 0; v < V; v++) acc += M[v * V + u] * xt[v * F + f];
                }
                rhs[idx] = acc;
            }
            __syncthreads();
            for (int idx = tid; idx < V * FC; idx += 256) {
                int u = idx / FC, o = idx - u * FC;
                float acc = 0;
                #pragma unroll
                for (int f = 0; f < F; f++) acc += rhs[u * F + f] * Th[(kk * F + f) * FC + o];
                z[idx] += acc;
            }
            __syncthreads();
        }
        float* outp = ws + RING + (((size_t)sel * B + b) * RS + slot) * V * FC;
        for (int idx = tid; idx < V * FC; idx += 256) outp[idx] = fmaxf(z[idx], 0.f);
        __syncthreads();
    }
}

// -------- conv(3x1) + bias + layernorm(FT) + store; block per (sel, b, t) --------
// Register-tiled GEMM: out[ft][v] = sum_{k=(c,kt)} W[k][ft] * R[k][v].
// Thread (tf,tv) owns a 4ft x 4v tile; ring staged TRANSPOSED [kt][c][v+pad] so the
// R-read is a lane-DISTINCT ds_read_b128 (16 FMA/LDS-instr, conflict-free) instead
// of the old wave-uniform broadcasts (4 FMA/instr). TG=1 + per-c W loads keep the
// live register set ~50 VGPRs (Round-3's 24xfloat4 W buffers spilled to scratch:
// 715 MB WRITE_SIZE/dispatch).
constexpr int RST = 68;   // transposed row stride: 16B-aligned, pads v to 68
__global__ __launch_bounds__(256) void k_conv(const float* ws, void* outv, int t0) {
    __shared__ float ring_s[3 * 64 * RST];          // [kt][c][v+pad] = 51 KiB
    __shared__ float red_s[2][16][64];              // LN partials over tf-groups (8 KiB)
    __shared__ float mus[64], rsg[64];
    int blk = blockIdx.x;
    int sel = (blk >= B * CH) ? 1 : 0;
    int r0  = blk - sel * B * CH;
    int b = r0 / CH, dt = r0 - b * CH;
    int t = t0 + dt;
    if (t >= T) return;                           // block-uniform (before any barrier)
    int tid = threadIdx.x;
    int tv = tid & 15, tf = tid >> 4;             // v-quad, ft-quad
    bool isf = ws[FLAG] != 0.f;
    const float4* wt4 = (const float4*)(ws + (sel ? P_WTSD : P_WTGL)); // [c*3+kt][ft/4]
    const float* ringb = ws + RING + (((size_t)sel * B + b) * RS + dt) * V * FC;
    // zero pad columns (v=62..67): no v-bounds checks in main loop
    for (int i = tid; i < 3 * 64 * (RST - V); i += 256) {
        int sc = i / (RST - V), p = i - sc * (RST - V);
        ring_s[sc * RST + V + p] = 0.f;
    }
    // stage 3 slots, transposed [v][c] -> [c][v]; invalid halo slots zeroed
    for (int i = tid; i < 3 * V * FC; i += 256) {
        int s = i / (V * FC), e = i - s * (V * FC);
        int v = e >> 6, c = e & 63;
        int tglob = t - 1 + s;
        float val = (tglob >= 0 && tglob < T) ? ringb[i] : 0.f;
        ring_s[(s * 64 + c) * RST + v] = val;
    }
    __syncthreads();

    float acc[4][4];                              // [ft-sub a][v-sub d]
    #pragma unroll
    for (int a = 0; a < 4; a++)
        #pragma unroll
        for (int d = 0; d < 4; d++) acc[a][d] = 0.f;

    const float* rbase = ring_s + 4 * tv;
    #define LD4_(dst, src) { float4 _t4 = (src); dst[0] = _t4.x; dst[1] = _t4.y; dst[2] = _t4.z; dst[3] = _t4.w; }
    #pragma unroll 4
    for (int c = 0; c < 64; c++) {
        float w0[4], w1[4], w2[4], q0[4], q1[4], q2[4];
        LD4_(w0, wt4[(c * 3 + 0) * 16 + tf]);
        LD4_(w1, wt4[(c * 3 + 1) * 16 + tf]);
        LD4_(w2, wt4[(c * 3 + 2) * 16 + tf]);
        LD4_(q0, *(const float4*)(rbase + c * RST));
        LD4_(q1, *(const float4*)(rbase + (64 + c) * RST));
        LD4_(q2, *(const float4*)(rbase + (128 + c) * RST));
        #pragma unroll
        for (int a = 0; a < 4; a++)
            #pragma unroll
            for (int d = 0; d < 4; d++)
                acc[a][d] += w0[a] * q0[d] + w1[a] * q1[d] + w2[a] * q2[d];
    }
    #undef LD4_

    // epilogue: + bias, layernorm over ft (LDS tree across 16 tf-groups), store
    float bcs[4], ggs[4], bbs[4];
    #pragma unroll
    for (int a = 0; a < 4; a++) {
        bcs[a] = ws[(sel ? P_BCSD : P_BCGL) + 4 * tf + a];
        ggs[a] = ws[(sel ? P_GSD  : P_GGL)  + 4 * tf + a];
        bbs[a] = ws[(sel ? P_BESD : P_BEGL) + 4 * tf + a];
    }
    float ps[4] = {0, 0, 0, 0}, pq[4] = {0, 0, 0, 0};
    #pragma unroll
    for (int a = 0; a < 4; a++)
        #pragma unroll
        for (int d = 0; d < 4; d++) {
            float v = acc[a][d] + bcs[a];
            acc[a][d] = v;
            ps[d] += v; pq[d] += v * v;
        }
    #pragma unroll
    for (int d = 0; d < 4; d++) {
        red_s[0][tf][4 * tv + d] = ps[d];
        red_s[1][tf][4 * tv + d] = pq[d];
    }
    __syncthreads();
    if (tid < 64) {
        float s = 0.f, q = 0.f;
        #pragma unroll
        for (int g = 0; g < 16; g++) { s += red_s[0][g][tid]; q += red_s[1][g][tid]; }
        float mu  = s * (1.f / 64.f);
        float var = q * (1.f / 64.f) - mu * mu;
        mus[tid] = mu; rsg[tid] = rsqrtf(var + 1e-5f);
    }
    __syncthreads();
    size_t obase = (size_t)sel * B * FT * T * V;
    #pragma unroll
    for (int a = 0; a < 4; a++) {
        int ft = 4 * tf + a;
        size_t orow = obase + (((size_t)(b * FT + ft)) * T + t) * V;
        #pragma unroll
        for (int d = 0; d < 4; d++) {
            int v = 4 * tv + d;
            if (v < V) {
                float val = (acc[a][d] - mus[v]) * rsg[v] * ggs[a] + bbs[a];
                if (isf) ((float*)outv)[orow + v] = val;
                else     ((bf16*)outv)[orow + v] = __float2bfloat16(val);
            }
        }
    }
}

extern "C" void kernel_launch(void* const* d_in, const int* in_sizes, int n_in,
                              void* d_out, int out_size, void* d_ws, size_t ws_size,
                              hipStream_t stream) {
    float* ws = (float*)d_ws;
    hipLaunchKernelGGL(k_dtype, dim3(1), dim3(256), 0, stream, d_in[0], ws);
    hipLaunchKernelGGL(k_prep, dim3(256), dim3(256), 0, stream,
                       d_in[0], d_in[1], d_in[2], d_in[3], d_in[4], d_in[5], d_in[6],
                       d_in[7], d_in[8], d_in[9], d_in[10], d_in[11], d_in[12], d_in[13],
                       d_in[14], d_in[15], d_in[16], d_in[17], d_in[18], d_in[19],
                       d_in[20], d_in[21], d_in[22], ws);
    hipLaunchKernelGGL(k_tlhs,  dim3(BT),        dim3(64),  0, stream, ws);
    hipLaunchKernelGGL(k_trhs,  dim3(512),       dim3(256), 0, stream, ws);
    hipLaunchKernelGGL(k_prod,  dim3(BT),        dim3(256), 0, stream, ws);
    hipLaunchKernelGGL(k_sraw,  dim3(B * NIG),   dim3(256), 0, stream, ws);
    hipLaunchKernelGGL(k_tsm,   dim3(B * KTI),   dim3(256), 0, stream, ws);
    hipLaunchKernelGGL(k_y,     dim3(B * NPG),   dim3(256), 0, stream, ws);
    hipLaunchKernelGGL(k_xw,    dim3(B * PTI),   dim3(256), 0, stream, ws);
    hipLaunchKernelGGL(k_ssr,   dim3(512),       dim3(256), 0, stream, ws);
    hipLaunchKernelGGL(k_sprod, dim3(241),       dim3(256), 0, stream, ws);
    hipLaunchKernelGGL(k_satt,  dim3(B),         dim3(256), 0, stream, ws);
    for (int ci = 0; ci < NCHK; ci++) {
        int t0 = ci * CH;
        hipLaunchKernelGGL(k_cheb, dim3(B * RS),     dim3(256), 0, stream, ws, t0);
        hipLaunchKernelGGL(k_conv, dim3(B * CH * 2), dim3(256), 0, stream, ws, d_out, t0);
    }
}

// Round 6
// 1100.320 us; speedup vs baseline: 3.8896x; 1.3999x over previous
//
#include <hip/hip_runtime.h>
#include <hip/hip_bf16.h>
#include <math.h>

typedef __hip_bfloat16 bf16;

constexpr int B = 16, T = 265, V = 62, F = 5, Kc = 3, FC = 64, FT = 64, KT = 3;
constexpr int VF  = V * F;      // 310
constexpr int VV  = V * V;      // 3844
constexpr int TT  = T * T;      // 70225
constexpr int TVF = T * V * F;  // 82150
constexpr int BT  = B * T;      // 4240

// ---------------- workspace layout (float offsets), params first ----------------
constexpr size_t FLAG  = 0;                          // dtype flag (0=bf16,1=f32)
constexpr size_t P_U1  = 4;
constexpr size_t P_U2  = P_U1 + 62;
constexpr size_t P_U3  = P_U2 + 310;
constexpr size_t P_BE  = P_U3 + 5;
constexpr size_t P_VE  = P_BE + 70225;
constexpr size_t P_W1  = P_VE + 70225;
constexpr size_t P_W2  = P_W1 + 265;
constexpr size_t P_W3  = P_W2 + 1325;
constexpr size_t P_BS  = P_W3 + 5;
constexpr size_t P_VS  = P_BS + 3844;
constexpr size_t P_AGL = P_VS + 3844;
constexpr size_t P_THGL= P_AGL + 5;
constexpr size_t P_THSD= P_THGL + 960;
constexpr size_t P_CHEB= P_THSD + 960;               // (K,V,V)
constexpr size_t P_WTGL= P_CHEB + 11532;             // transposed [fc*3+kt][ft]
constexpr size_t P_BCGL= P_WTGL + 12288;
constexpr size_t P_WTSD= P_BCGL + 64;
constexpr size_t P_BCSD= P_WTSD + 12288;
constexpr size_t P_GGL = P_BCSD + 64;
constexpr size_t P_BEGL= P_GGL + 64;
constexpr size_t P_GSD = P_BEGL + 64;
constexpr size_t P_BESD= P_GSD + 64;
constexpr size_t PEND  = (P_BESD + 64 + 3) & ~(size_t)3;
// working buffers
constexpr size_t XF    = PEND;                       // (B,T,V,F) fp32 x
constexpr size_t TLHS  = XF    + (size_t)B*T*V*F;    // (B,T,V)
constexpr size_t TRHS  = TLHS  + (size_t)B*T*V;      // (B,V,T)
constexpr size_t PRODT = TRHS  + (size_t)B*V*T;      // (B,T,T)
constexpr size_t SRAWT = PRODT + (size_t)B*TT;       // (B,T,T) -> TAtt in place
constexpr size_t YBUF  = SRAWT + (size_t)B*TT;       // (B,VF,T) == x_TAtt (B,T,V,F)
constexpr size_t XWOF  = YBUF  + (size_t)B*VF*T;     // (B,V,F)
constexpr size_t SLHS  = XWOF  + (size_t)B*V*F;      // (B,V,T)
constexpr size_t SRHS  = SLHS  + (size_t)B*V*T;      // (B,T,V)
constexpr size_t SATT  = SRHS  + (size_t)B*T*V;      // (B,V,V)
constexpr size_t SPROD = PRODT;                      // alias: PRODT dead after k_sraw
// full GCN intermediate (2,B,T,V,FC) = 134.6 MB; ws proven >= 538 MB by the
// harness poison-fill WRITE_SIZE. Replaces the old chunked ring (tail waste:
// 544-block dispatches on 512 resident slots = ~2x idle).
constexpr size_t GCN   = SATT  + (size_t)B*V*V;

static __device__ __forceinline__ float sigmoidf_(float x) {
    return 1.f / (1.f + expf(-x));
}

// -------- dtype probe: are inputs bf16 or f32? --------
__global__ void k_dtype(const void* x, float* ws) {
    __shared__ int cnt;
    if (threadIdx.x == 0) cnt = 0;
    __syncthreads();
    int bad = 0;
    const bf16* p = (const bf16*)x;
    for (int i = threadIdx.x; i < 4096; i += 256) {
        float v = __bfloat162float(p[i]);
        if (!isfinite(v) || fabsf(v) > 1e3f || (v != 0.f && fabsf(v) < 1e-10f)) bad++;
    }
    atomicAdd(&cnt, bad);
    __syncthreads();
    if (threadIdx.x == 0) ws[FLAG] = (cnt > 100) ? 1.f : 0.f;
}

static __device__ __forceinline__ void cvtany(const void* s, float* d, int n,
                                              int tid, int st, bool isf) {
    if (isf) {
        const float* p = (const float*)s;
        for (int i = tid; i < n; i += st) d[i] = p[i];
    } else {
        const bf16* p = (const bf16*)s;
        for (int i = tid; i < n; i += st) d[i] = __bfloat162float(p[i]);
    }
}

// -------- convert all inputs to fp32 workspace (Wc transposed) --------
__global__ void k_prep(const void* x, const void* U1, const void* U2, const void* U3,
                       const void* bE, const void* Ve, const void* W1, const void* W2,
                       const void* W3, const void* bS, const void* Vs, const void* aGL,
                       const void* ThGL, const void* ThSD, const void* Cheb,
                       const void* WcGL, const void* bcGL, const void* WcSD, const void* bcSD,
                       const void* gGL, const void* beGL, const void* gSD, const void* beSD,
                       float* ws) {
    int tid = blockIdx.x * blockDim.x + threadIdx.x;
    int st  = gridDim.x * blockDim.x;
    bool isf = ws[FLAG] != 0.f;
    cvtany(x,    ws + XF,    B*T*V*F, tid, st, isf);
    cvtany(U1,   ws + P_U1,  62,    tid, st, isf);
    cvtany(U2,   ws + P_U2,  310,   tid, st, isf);
    cvtany(U3,   ws + P_U3,  5,     tid, st, isf);
    cvtany(bE,   ws + P_BE,  70225, tid, st, isf);
    cvtany(Ve,   ws + P_VE,  70225, tid, st, isf);
    cvtany(W1,   ws + P_W1,  265,   tid, st, isf);
    cvtany(W2,   ws + P_W2,  1325,  tid, st, isf);
    cvtany(W3,   ws + P_W3,  5,     tid, st, isf);
    cvtany(bS,   ws + P_BS,  3844,  tid, st, isf);
    cvtany(Vs,   ws + P_VS,  3844,  tid, st, isf);
    cvtany(aGL,  ws + P_AGL, 5,     tid, st, isf);
    cvtany(ThGL, ws + P_THGL, 960,  tid, st, isf);
    cvtany(ThSD, ws + P_THSD, 960,  tid, st, isf);
    cvtany(Cheb, ws + P_CHEB, 11532, tid, st, isf);
    cvtany(bcGL, ws + P_BCGL, 64, tid, st, isf);
    cvtany(bcSD, ws + P_BCSD, 64, tid, st, isf);
    cvtany(gGL,  ws + P_GGL,  64, tid, st, isf);
    cvtany(beGL, ws + P_BEGL, 64, tid, st, isf);
    cvtany(gSD,  ws + P_GSD,  64, tid, st, isf);
    cvtany(beSD, ws + P_BESD, 64, tid, st, isf);
    // Wc (FT,FC,KT,1) -> [fc*3+kt][ft]
    for (int i = tid; i < 12288; i += st) {
        int ft = i / 192, r = i - ft * 192;
        float g, s;
        if (isf) { g = ((const float*)WcGL)[i]; s = ((const float*)WcSD)[i]; }
        else     { g = __bfloat162float(((const bf16*)WcGL)[i]);
                   s = __bfloat162float(((const bf16*)WcSD)[i]); }
        ws[P_WTGL + (size_t)r * 64 + ft] = g;
        ws[P_WTSD + (size_t)r * 64 + ft] = s;
    }
}

// -------- t_lhs[b,t,j] = (sum_v x*U1) @ U2 ; one block per (b,t) --------
__global__ void k_tlhs(float* ws) {
    __shared__ float sh[V * F];
    __shared__ float xu[F];
    int blk = blockIdx.x; int b = blk / T, t = blk - b * T;
    int tid = threadIdx.x;
    if (tid < V) {
        float u1v = ws[P_U1 + tid];
        const float* xr = ws + XF + ((size_t)b * T + t) * VF + tid * F;
        #pragma unroll
        for (int f = 0; f < F; f++) sh[tid * F + f] = xr[f] * u1v;
    }
    __syncthreads();
    if (tid < F) {
        float s = 0;
        for (int v = 0; v < V; v++) s += sh[v * F + tid];
        xu[tid] = s;
    }
    __syncthreads();
    if (tid < V) {
        float acc = 0;
        #pragma unroll
        for (int f = 0; f < F; f++) acc += xu[f] * ws[P_U2 + f * V + tid];
        ws[TLHS + ((size_t)b * T + t) * V + tid] = acc;
    }
}

// -------- t_rhs[b,v,t] = sum_f x[b,t,v,f]*U3[f] --------
__global__ void k_trhs(float* ws) {
    int i0 = blockIdx.x * blockDim.x + threadIdx.x;
    int st = gridDim.x * blockDim.x;
    for (int idx = i0; idx < B * V * T; idx += st) {
        int b = idx / (V * T); int r = idx - b * V * T; int v = r / T; int t = r - v * T;
        const float* xr = ws + XF + ((size_t)b * T + t) * VF + v * F;
        float acc = 0;
        #pragma unroll
        for (int f = 0; f < F; f++) acc += xr[f] * ws[P_U3 + f];
        ws[TRHS + idx] = acc;
    }
}

// -------- prod[b,i,k] = sum_j tlhs[b,i,j]*trhs[b,j,k] ; block per (b,i) --------
__global__ __launch_bounds__(256) void k_prod(float* ws) {
    __shared__ float ls[V];
    int blk = blockIdx.x; int b = blk / T, i = blk - b * T;
    int k = threadIdx.x;
    int k2 = min(k + 256, T - 1); bool w2 = (k + 256) < T;
    const float* lr = ws + TLHS + ((size_t)b * T + i) * V;
    const float* rr = ws + TRHS + (size_t)b * V * T;
    if (k < V) ls[k] = lr[k];
    __syncthreads();
    float a0 = 0, a1 = 0;
    for (int j = 0; j < V; j++) {
        float l = ls[j];
        a0 += l * rr[(size_t)j * T + k];
        a1 += l * rr[(size_t)j * T + k2];
    }
    float* o = ws + PRODT + (size_t)b * TT + (size_t)i * T;
    o[k] = a0;
    if (w2) o[k2] = a1;
}

// -------- Sraw = sigmoid(V_e @ prod + b_e), 4 rows per block --------
constexpr int IG = 4, NIG = (T + IG - 1) / IG; // 67
__global__ __launch_bounds__(256) void k_sraw(float* ws) {
    __shared__ float ve[IG * T];    // 4 rows x 265 = 4.2 KB
    int blk = blockIdx.x; int b = blk / NIG; int i0 = (blk - b * NIG) * IG;
    int k = threadIdx.x;
    int k2 = min(k + 256, T - 1); bool w2 = (k + 256) < T;
    const float* pr = ws + PRODT + (size_t)b * TT;
    for (int i = k; i < IG * T; i += 256) {
        int q = i / T, j = i - q * T;
        int ii = min(i0 + q, T - 1);
        ve[i] = ws[P_VE + (size_t)ii * T + j];
    }
    __syncthreads();
    float a0[IG] = {0, 0, 0, 0}, a1[IG] = {0, 0, 0, 0};
    for (int j = 0; j < T; j++) {
        const float* row = pr + (size_t)j * T;
        float r0 = row[k], r1 = row[k2];
        #pragma unroll
        for (int q = 0; q < IG; q++) {
            float v = ve[q * T + j];
            a0[q] += v * r0; a1[q] += v * r1;
        }
    }
    #pragma unroll
    for (int q = 0; q < IG; q++) {
        int i = i0 + q;
        if (i < T) {
            float* o = ws + SRAWT + (size_t)b * TT + (size_t)i * T;
            o[k] = sigmoidf_(a0[q] + ws[P_BE + (size_t)i * T + k]);
            if (w2) o[k2] = sigmoidf_(a1[q] + ws[P_BE + (size_t)i * T + k2]);
        }
    }
}

// -------- column softmax, tiled & coalesced: block per (b, 64-wide k tile) --------
constexpr int KTI = (T + 63) / 64;  // 5
__global__ __launch_bounds__(256) void k_tsm(float* ws) {
    __shared__ float red[4][64];
    __shared__ float cstat[64];
    int blk = blockIdx.x; int b = blk / KTI; int k0 = (blk - b * KTI) * 64;
    int ks = threadIdx.x & 63; int isub = threadIdx.x >> 6;
    int k = k0 + ks; bool act = k < T;
    float* S = ws + SRAWT + (size_t)b * TT;
    float m = -1e30f;
    if (act) for (int i = isub; i < T; i += 4) m = fmaxf(m, S[(size_t)i * T + k]);
    red[isub][ks] = m;
    __syncthreads();
    if (isub == 0)
        cstat[ks] = fmaxf(fmaxf(red[0][ks], red[1][ks]), fmaxf(red[2][ks], red[3][ks]));
    __syncthreads();
    m = cstat[ks];
    float s = 0;
    if (act) for (int i = isub; i < T; i += 4) s += expf(S[(size_t)i * T + k] - m);
    __syncthreads();
    red[isub][ks] = s;
    __syncthreads();
    if (isub == 0)
        cstat[ks] = 1.f / (red[0][ks] + red[1][ks] + red[2][ks] + red[3][ks]);
    __syncthreads();
    float inv = cstat[ks];
    if (act) for (int i = isub; i < T; i += 4) {
        size_t o = (size_t)i * T + k;
        S[o] = expf(S[o] - m) * inv;
    }
}

// -------- y[b,p,t] = sum_s x_flat[b,p,s]*TAtt[b,s,t]; 8 p per block --------
constexpr int PG = 8, NPG = (VF + PG - 1) / PG; // 39
__global__ __launch_bounds__(256) void k_y(float* ws) {
    __shared__ float xs[T * PG];    // 265 x 8 = 8.3 KB
    int blk = blockIdx.x; int b = blk / NPG; int p0 = (blk - b * NPG) * PG;
    int t = threadIdx.x;
    int t2 = min(t + 256, T - 1); bool w2 = (t + 256) < T;
    const float* xb = ws + XF + (size_t)b * TVF;
    const float* ta = ws + SRAWT + (size_t)b * TT;
    for (int i = threadIdx.x; i < T * PG; i += 256) {
        int s = i >> 3, j = i & 7;   // tail lanes read past x into TLHS: finite, unused
        xs[i] = xb[(size_t)s * VF + p0 + j];
    }
    __syncthreads();
    float a0[PG], a1[PG];
    #pragma unroll
    for (int j = 0; j < PG; j++) { a0[j] = 0; a1[j] = 0; }
    for (int s = 0; s < T; s++) {
        float ta0 = ta[(size_t)s * T + t];
        float ta1 = ta[(size_t)s * T + t2];
        const float* xr = xs + s * PG;
        #pragma unroll
        for (int j = 0; j < PG; j++) {  // broadcast LDS reads (free)
            float xv = xr[j];
            a0[j] += xv * ta0; a1[j] += xv * ta1;
        }
    }
    float* yb = ws + YBUF + (size_t)b * VF * T;
    #pragma unroll
    for (int j = 0; j < PG; j++) {
        if (p0 + j < VF) {
            yb[(size_t)(p0 + j) * T + t] = a0[j];
            if (w2) yb[(size_t)(p0 + j) * T + t2] = a1[j];
        }
    }
}

// -------- xw[b,v,f] = sum_t x_TAtt[b,t,v,f]*W1[t]; block per (b, 64-wide p tile) --------
constexpr int PTI = (VF + 63) / 64;  // 5
__global__ __launch_bounds__(256) void k_xw(float* ws) {
    __shared__ float red[4][64];
    __shared__ float w1s[T];
    int blk = blockIdx.x; int b = blk / PTI; int p0 = (blk - b * PTI) * 64;
    int ps = threadIdx.x & 63; int tsub = threadIdx.x >> 6;
    int p = p0 + ps; bool act = p < VF;
    for (int i = threadIdx.x; i < T; i += 256) w1s[i] = ws[P_W1 + i];
    const float* yb = ws + YBUF + (size_t)b * TVF;
    __syncthreads();
    float acc = 0;
    if (act) for (int t = tsub; t < T; t += 4) acc += yb[(size_t)t * VF + p] * w1s[t];
    red[tsub][ps] = acc;
    __syncthreads();
    if (tsub == 0 && act)
        ws[XWOF + (size_t)b * VF + p] = red[0][ps] + red[1][ps] + red[2][ps] + red[3][ps];
}

// -------- merged s_lhs + s_rhs --------
__global__ void k_ssr(float* ws) {
    int i0 = blockIdx.x * blockDim.x + threadIdx.x;
    int st = gridDim.x * blockDim.x;
    for (int idx = i0; idx < B * V * T; idx += st) {   // s_lhs[b,v,j]
        int b = idx / (V * T); int r = idx - b * V * T; int v = r / T; int j = r - v * T;
        float acc = 0;
        #pragma unroll
        for (int f = 0; f < F; f++)
            acc += ws[XWOF + (size_t)b * VF + v * F + f] * ws[P_W2 + (size_t)f * T + j];
        ws[SLHS + idx] = acc;
    }
    for (int idx = i0; idx < B * T * V; idx += st) {   // s_rhs[b,t,v]
        int b = idx / (T * V); int r = idx - b * T * V; int t = r / V; int v = r - t * V;
        const float* yr = ws + YBUF + (size_t)b * TVF + (size_t)t * VF + v * F;
        float acc = 0;
        #pragma unroll
        for (int f = 0; f < F; f++) acc += yr[f] * ws[P_W3 + f];
        ws[SRHS + idx] = acc;
    }
}

// -------- sp[b,i,k] = sum_j slhs[b,i,j]*srhs[b,j,k] (grid-stride, coalesced) --------
__global__ void k_sprod(float* ws) {
    int i0 = blockIdx.x * blockDim.x + threadIdx.x;
    int st = gridDim.x * blockDim.x;
    for (int idx = i0; idx < B * VV; idx += st) {
        int b = idx / VV; int r = idx - b * VV; int i = r / V; int k = r - i * V;
        const float* sl = ws + SLHS + (size_t)b * V * T + (size_t)i * T;
        const float* sr = ws + SRHS + (size_t)b * T * V;
        float acc = 0;
        for (int j = 0; j < T; j++) acc += sl[j] * sr[(size_t)j * V + k];
        ws[SPROD + idx] = acc;
    }
}

// -------- SAtt = colsoftmax(sigmoid(Vs@sp + bs)) ; block per b (small) --------
__global__ __launch_bounds__(256) void k_satt(float* ws) {
    __shared__ float sp[VV];
    __shared__ float s2[VV];
    int b = blockIdx.x, tid = threadIdx.x;
    for (int i = tid; i < VV; i += 256) sp[i] = ws[SPROD + (size_t)b * VV + i];
    __syncthreads();
    for (int idx = tid; idx < VV; idx += 256) {
        int i = idx / V, k = idx - i * V;
        float acc = 0;
        for (int j = 0; j < V; j++) acc += ws[P_VS + (size_t)i * V + j] * sp[j * V + k];
        s2[idx] = sigmoidf_(acc + ws[P_BS + idx]);
    }
    __syncthreads();
    if (tid < V) {
        int k = tid;
        float m = -1e30f;
        for (int i = 0; i < V; i++) m = fmaxf(m, s2[i * V + k]);
        float sum = 0;
        for (int i = 0; i < V; i++) sum += expf(s2[i * V + k] - m);
        float inv = 1.f / sum;
        for (int i = 0; i < V; i++)
            ws[SATT + (size_t)b * VV + i * V + k] = expf(s2[i * V + k] - m) * inv;
    }
}

// -------- per-(b,t) fused graph-learning + Chebyshev convs -> full GCN buffer --------
// Single launch, grid B*T (was 9 chunked launches of 544 blocks = ~2x tail waste on
// 512 resident slots). z moved LDS->registers (16/thread, static indices): LDS
// 64.5->48.6 KB -> 3 blocks/CU.
__global__ __launch_bounds__(256) void k_cheb(float* ws) {
    __shared__ float xt[VF];
    __shared__ float sa[VV];
    __shared__ float bufA[VV];   // Sg -> T2 -> M2 -> (sel1 Mk)
    __shared__ float bufB[VV];   // A -> L -> M1
    __shared__ float rhs[VF];
    __shared__ float rsum[64];
    __shared__ float ag[8];
    int blk = blockIdx.x; int b = blk / T, t = blk - b * T;
    int tid = threadIdx.x;
    for (int i = tid; i < VF; i += 256) xt[i] = ws[XF + (size_t)b * TVF + (size_t)t * VF + i];
    if (tid < F) ag[tid] = ws[P_AGL + tid];
    for (int i = tid; i < VV; i += 256) sa[i] = ws[SATT + (size_t)b * VV + i];
    __syncthreads();
    for (int idx = tid; idx < VV; idx += 256) {   // Sg = exp(|xu-xv|.a)
        int u = idx / V, v = idx - u * V;
        float acc = 0;
        #pragma unroll
        for (int f = 0; f < F; f++) acc += fabsf(xt[u * F + f] - xt[v * F + f]) * ag[f];
        bufA[idx] = expf(acc);
    }
    __syncthreads();
    if (tid < V) { float s = 0; for (int v = 0; v < V; v++) s += bufA[tid * V + v]; rsum[tid] = s; }
    __syncthreads();
    for (int idx = tid; idx < VV; idx += 256) {   // A = min(Sgn, Sgn^T)
        int u = idx / V, v = idx - u * V;
        float a = bufA[u * V + v] / rsum[u];
        float s = bufA[v * V + u] / rsum[v];
        bufB[idx] = fminf(a, s);
    }
    __syncthreads();
    if (tid < V) { float s = 0; for (int v = 0; v < V; v++) s += bufB[tid * V + v]; rsum[tid] = s; }
    __syncthreads();
    for (int idx = tid; idx < VV; idx += 256) {   // L = diag(d-1) - A
        int u = idx / V, v = idx - u * V;
        bufB[idx] = ((u == v) ? (rsum[u] - 1.f) : 0.f) - bufB[idx];
    }
    __syncthreads();
    {   // T2 = 2 L@L - I, register-tiled 4x4 (2 MAC per LDS read)
        int tu = tid >> 4, tv = tid & 15;
        float acc4[4][4];
        #pragma unroll
        for (int a = 0; a < 4; a++)
            #pragma unroll
            for (int c = 0; c < 4; c++) acc4[a][c] = 0.f;
        for (int k = 0; k < V; k++) {
            float av[4], bv[4];
            #pragma unroll
            for (int d = 0; d < 4; d++) {
                int u = 4 * tu + d;
                av[d] = (u < V) ? bufB[u * V + k] : 0.f;
                int v = 4 * tv + d;
                bv[d] = (v < V) ? bufB[k * V + v] : 0.f;
            }
            #pragma unroll
            for (int a = 0; a < 4; a++)
                #pragma unroll
                for (int c = 0; c < 4; c++) acc4[a][c] += av[a] * bv[c];
        }
        __syncthreads();
        #pragma unroll
        for (int a = 0; a < 4; a++) {
            int u = 4 * tu + a;
            if (u >= V) continue;
            #pragma unroll
            for (int c = 0; c < 4; c++) {
                int v = 4 * tv + c;
                if (v >= V) continue;
                bufA[u * V + v] = 2.f * acc4[a][c] - ((u == v) ? 1.f : 0.f);
            }
        }
    }
    __syncthreads();
    for (int idx = tid; idx < VV; idx += 256) {   // M1 = L.SA, M2 = T2.SA (elementwise)
        float s = sa[idx];
        bufB[idx] *= s;
        bufA[idx] *= s;
    }
    __syncthreads();
    for (int sel = 0; sel < 2; sel++) {
        float zreg[16];
        #pragma unroll
        for (int i = 0; i < 16; i++) zreg[i] = 0.f;
        const float* Th = ws + (sel ? P_THSD : P_THGL);
        for (int kk = 0; kk < Kc; kk++) {
            if (sel == 1 && kk > 0) {   // stage Mk = C_kk . SA into bufA
                const float* C = ws + P_CHEB + (size_t)kk * VV;
                for (int idx = tid; idx < VV; idx += 256) bufA[idx] = C[idx] * sa[idx];
                __syncthreads();
            }
            for (int idx = tid; idx < VF; idx += 256) {  // rhs[u,f] = sum_v M[v,u]*x[v,f]
                int u = idx / F, f = idx - u * F;
                float acc = 0;
                if (kk == 0) {
                    acc = sa[u * V + u] * xt[u * F + f];   // T0 = I (both GL and SD)
                } else {
                    const float* M = (sel == 0 && kk == 1) ? bufB : bufA;
                    for (int v = 0; v < V; v++) acc += M[v * V + u] * xt[v * F + f];
                }
                rhs[idx] = acc;
            }
            __syncthreads();
            #pragma unroll
            for (int i = 0; i < 16; i++) {              // z += rhs @ Th (registers)
                int idx = i * 256 + tid;
                if (idx < V * FC) {
                    int u = idx >> 6, o = idx & 63;
                    float acc = 0;
                    #pragma unroll
                    for (int f = 0; f < F; f++) acc += rhs[u * F + f] * Th[(kk * F + f) * FC + o];
                    zreg[i] += acc;
                }
            }
            __syncthreads();   // protect rhs before next kk overwrites it
        }
        float* outp = ws + GCN + (((size_t)sel * B + b) * T + t) * V * FC;
        #pragma unroll
        for (int i = 0; i < 16; i++) {
            int idx = i * 256 + tid;
            if (idx < V * FC) outp[idx] = fmaxf(zreg[i], 0.f);
        }
    }
}

// -------- conv(3x1) + bias + layernorm(FT) + store; block per (sel, b, t) --------
// Register-tiled GEMM (proven Round 4): thread (tf,tv) owns a 4ft x 4v tile; slots
// (t-1,t,t+1) staged TRANSPOSED [kt][c][v+pad] -> lane-distinct ds_read_b128.
// Single launch over the full GCN buffer (slots contiguous in memory).
constexpr int RST = 68;   // transposed row stride: 16B-aligned, pads v to 68
__global__ __launch_bounds__(256) void k_conv(const float* ws, void* outv) {
    __shared__ float ring_s[3 * 64 * RST];          // [kt][c][v+pad] = 51 KiB
    __shared__ float red_s[2][16][64];              // LN partials over tf-groups (8 KiB)
    __shared__ float mus[64], rsg[64];
    int blk = blockIdx.x;
    int sel = (blk >= BT) ? 1 : 0;
    int r0  = blk - sel * BT;
    int b = r0 / T, t = r0 - b * T;
    int tid = threadIdx.x;
    int tv = tid & 15, tf = tid >> 4;             // v-quad, ft-quad
    bool isf = ws[FLAG] != 0.f;
    const float4* wt4 = (const float4*)(ws + (sel ? P_WTSD : P_WTGL)); // [c*3+kt][ft/4]
    const float* ringb = ws + GCN + (((size_t)sel * B + b) * T + (t - 1)) * V * FC;
    // zero pad columns (v=62..67): no v-bounds checks in main loop
    for (int i = tid; i < 3 * 64 * (RST - V); i += 256) {
        int sc = i / (RST - V), p = i - sc * (RST - V);
        ring_s[sc * RST + V + p] = 0.f;
    }
    // stage 3 slots, transposed [v][c] -> [c][v]; invalid edge slots zeroed
    for (int i = tid; i < 3 * V * FC; i += 256) {
        int s = i / (V * FC), e = i - s * (V * FC);
        int v = e >> 6, c = e & 63;
        int tglob = t - 1 + s;
        float val = (tglob >= 0 && tglob < T) ? ringb[i] : 0.f;
        ring_s[(s * 64 + c) * RST + v] = val;
    }
    __syncthreads();

    float acc[4][4];                              // [ft-sub a][v-sub d]
    #pragma unroll
    for (int a = 0; a < 4; a++)
        #pragma unroll
        for (int d = 0; d < 4; d++) acc[a][d] = 0.f;

    const float* rbase = ring_s + 4 * tv;
    #define LD4_(dst, src) { float4 _t4 = (src); dst[0] = _t4.x; dst[1] = _t4.y; dst[2] = _t4.z; dst[3] = _t4.w; }
    #pragma unroll 4
    for (int c = 0; c < 64; c++) {
        float w0[4], w1[4], w2[4], q0[4], q1[4], q2[4];
        LD4_(w0, wt4[(c * 3 + 0) * 16 + tf]);
        LD4_(w1, wt4[(c * 3 + 1) * 16 + tf]);
        LD4_(w2, wt4[(c * 3 + 2) * 16 + tf]);
        LD4_(q0, *(const float4*)(rbase + c * RST));
        LD4_(q1, *(const float4*)(rbase + (64 + c) * RST));
        LD4_(q2, *(const float4*)(rbase + (128 + c) * RST));
        #pragma unroll
        for (int a = 0; a < 4; a++)
            #pragma unroll
            for (int d = 0; d < 4; d++)
                acc[a][d] += w0[a] * q0[d] + w1[a] * q1[d] + w2[a] * q2[d];
    }
    #undef LD4_

    // epilogue: + bias, layernorm over ft (LDS tree across 16 tf-groups), store
    float bcs[4], ggs[4], bbs[4];
    #pragma unroll
    for (int a = 0; a < 4; a++) {
        bcs[a] = ws[(sel ? P_BCSD : P_BCGL) + 4 * tf + a];
        ggs[a] = ws[(sel ? P_GSD  : P_GGL)  + 4 * tf + a];
        bbs[a] = ws[(sel ? P_BESD : P_BEGL) + 4 * tf + a];
    }
    float ps[4] = {0, 0, 0, 0}, pq[4] = {0, 0, 0, 0};
    #pragma unroll
    for (int a = 0; a < 4; a++)
        #pragma unroll
        for (int d = 0; d < 4; d++) {
            float v = acc[a][d] + bcs[a];
            acc[a][d] = v;
            ps[d] += v; pq[d] += v * v;
        }
    #pragma unroll
    for (int d = 0; d < 4; d++) {
        red_s[0][tf][4 * tv + d] = ps[d];
        red_s[1][tf][4 * tv + d] = pq[d];
    }
    __syncthreads();
    if (tid < 64) {
        float s = 0.f, q = 0.f;
        #pragma unroll
        for (int g = 0; g < 16; g++) { s += red_s[0][g][tid]; q += red_s[1][g][tid]; }
        float mu  = s * (1.f / 64.f);
        float var = q * (1.f / 64.f) - mu * mu;
        mus[tid] = mu; rsg[tid] = rsqrtf(var + 1e-5f);
    }
    __syncthreads();
    size_t obase = (size_t)sel * B * FT * T * V;
    #pragma unroll
    for (int a = 0; a < 4; a++) {
        int ft = 4 * tf + a;
        size_t orow = obase + (((size_t)(b * FT + ft)) * T + t) * V;
        #pragma unroll
        for (int d = 0; d < 4; d++) {
            int v = 4 * tv + d;
            if (v < V) {
                float val = (acc[a][d] - mus[v]) * rsg[v] * ggs[a] + bbs[a];
                if (isf) ((float*)outv)[orow + v] = val;
                else     ((bf16*)outv)[orow + v] = __float2bfloat16(val);
            }
        }
    }
}

extern "C" void kernel_launch(void* const* d_in, const int* in_sizes, int n_in,
                              void* d_out, int out_size, void* d_ws, size_t ws_size,
                              hipStream_t stream) {
    float* ws = (float*)d_ws;
    hipLaunchKernelGGL(k_dtype, dim3(1), dim3(256), 0, stream, d_in[0], ws);
    hipLaunchKernelGGL(k_prep, dim3(256), dim3(256), 0, stream,
                       d_in[0], d_in[1], d_in[2], d_in[3], d_in[4], d_in[5], d_in[6],
                       d_in[7], d_in[8], d_in[9], d_in[10], d_in[11], d_in[12], d_in[13],
                       d_in[14], d_in[15], d_in[16], d_in[17], d_in[18], d_in[19],
                       d_in[20], d_in[21], d_in[22], ws);
    hipLaunchKernelGGL(k_tlhs,  dim3(BT),        dim3(64),  0, stream, ws);
    hipLaunchKernelGGL(k_trhs,  dim3(512),       dim3(256), 0, stream, ws);
    hipLaunchKernelGGL(k_prod,  dim3(BT),        dim3(256), 0, stream, ws);
    hipLaunchKernelGGL(k_sraw,  dim3(B * NIG),   dim3(256), 0, stream, ws);
    hipLaunchKernelGGL(k_tsm,   dim3(B * KTI),   dim3(256), 0, stream, ws);
    hipLaunchKernelGGL(k_y,     dim3(B * NPG),   dim3(256), 0, stream, ws);
    hipLaunchKernelGGL(k_xw,    dim3(B * PTI),   dim3(256), 0, stream, ws);
    hipLaunchKernelGGL(k_ssr,   dim3(512),       dim3(256), 0, stream, ws);
    hipLaunchKernelGGL(k_sprod, dim3(241),       dim3(256), 0, stream, ws);
    hipLaunchKernelGGL(k_satt,  dim3(B),         dim3(256), 0, stream, ws);
    hipLaunchKernelGGL(k_cheb,  dim3(BT),        dim3(256), 0, stream, ws);
    hipLaunchKernelGGL(k_conv,  dim3(2 * BT),    dim3(256), 0, stream, ws, d_out);
}

// Round 7
// 895.911 us; speedup vs baseline: 4.7771x; 1.2282x over previous
//
#include <hip/hip_runtime.h>
#include <hip/hip_bf16.h>
#include <math.h>

typedef __hip_bfloat16 bf16;

constexpr int B = 16, T = 265, V = 62, F = 5, Kc = 3, FC = 64, FT = 64, KT = 3;
constexpr int VF  = V * F;      // 310
constexpr int VV  = V * V;      // 3844
constexpr int TT  = T * T;      // 70225
constexpr int TVF = T * V * F;  // 82150
constexpr int BT  = B * T;      // 4240

// ---------------- workspace layout (float offsets), params first ----------------
constexpr size_t FLAG  = 0;                          // dtype flag (0=bf16,1=f32)
constexpr size_t P_U1  = 4;
constexpr size_t P_U2  = P_U1 + 62;
constexpr size_t P_U3  = P_U2 + 310;
constexpr size_t P_BE  = P_U3 + 5;
constexpr size_t P_VE  = P_BE + 70225;
constexpr size_t P_W1  = P_VE + 70225;
constexpr size_t P_W2  = P_W1 + 265;
constexpr size_t P_W3  = P_W2 + 1325;
constexpr size_t P_BS  = P_W3 + 5;
constexpr size_t P_VS  = P_BS + 3844;
constexpr size_t P_AGL = P_VS + 3844;
constexpr size_t P_THGL= P_AGL + 5;
constexpr size_t P_THSD= P_THGL + 960;
constexpr size_t P_CHEB= P_THSD + 960;               // (K,V,V)
constexpr size_t P_WTGL= P_CHEB + 11532;             // transposed [fc*3+kt][ft]
constexpr size_t P_BCGL= P_WTGL + 12288;
constexpr size_t P_WTSD= P_BCGL + 64;
constexpr size_t P_BCSD= P_WTSD + 12288;
constexpr size_t P_GGL = P_BCSD + 64;
constexpr size_t P_BEGL= P_GGL + 64;
constexpr size_t P_GSD = P_BEGL + 64;
constexpr size_t P_BESD= P_GSD + 64;
constexpr size_t PEND  = (P_BESD + 64 + 3) & ~(size_t)3;
// working buffers
constexpr size_t XF    = PEND;                       // (B,T,V,F) fp32 x
constexpr size_t TLHS  = XF    + (size_t)B*T*V*F;    // (B,T,V)
constexpr size_t TRHS  = TLHS  + (size_t)B*T*V;      // (B,V,T)
constexpr size_t PRODT = TRHS  + (size_t)B*V*T;      // (B,T,T)
constexpr size_t SRAWT = PRODT + (size_t)B*TT;       // (B,T,T) -> TAtt in place
constexpr size_t YBUF  = SRAWT + (size_t)B*TT;       // (B,VF,T) == x_TAtt (B,T,V,F)
constexpr size_t XWOF  = YBUF  + (size_t)B*VF*T;     // (B,V,F)
constexpr size_t SLHS  = XWOF  + (size_t)B*V*F;      // (B,V,T)
constexpr size_t SRHS  = SLHS  + (size_t)B*V*T;      // (B,T,V)
constexpr size_t SATT  = SRHS  + (size_t)B*T*V;      // (B,V,V)
constexpr size_t SPROD = PRODT;                      // alias: PRODT dead after k_sraw
// full GCN intermediate (2,B,T,V,FC) = 134.6 MB (ws proven >= 538 MB by harness fill)
constexpr size_t GCN   = SATT  + (size_t)B*V*V;

static __device__ __forceinline__ float sigmoidf_(float x) {
    return 1.f / (1.f + expf(-x));
}

// -------- dtype probe: are inputs bf16 or f32? --------
__global__ void k_dtype(const void* x, float* ws) {
    __shared__ int cnt;
    if (threadIdx.x == 0) cnt = 0;
    __syncthreads();
    int bad = 0;
    const bf16* p = (const bf16*)x;
    for (int i = threadIdx.x; i < 4096; i += 256) {
        float v = __bfloat162float(p[i]);
        if (!isfinite(v) || fabsf(v) > 1e3f || (v != 0.f && fabsf(v) < 1e-10f)) bad++;
    }
    atomicAdd(&cnt, bad);
    __syncthreads();
    if (threadIdx.x == 0) ws[FLAG] = (cnt > 100) ? 1.f : 0.f;
}

static __device__ __forceinline__ void cvtany(const void* s, float* d, int n,
                                              int tid, int st, bool isf) {
    if (isf) {
        const float* p = (const float*)s;
        for (int i = tid; i < n; i += st) d[i] = p[i];
    } else {
        const bf16* p = (const bf16*)s;
        for (int i = tid; i < n; i += st) d[i] = __bfloat162float(p[i]);
    }
}

// -------- convert all inputs to fp32 workspace (Wc transposed) --------
__global__ void k_prep(const void* x, const void* U1, const void* U2, const void* U3,
                       const void* bE, const void* Ve, const void* W1, const void* W2,
                       const void* W3, const void* bS, const void* Vs, const void* aGL,
                       const void* ThGL, const void* ThSD, const void* Cheb,
                       const void* WcGL, const void* bcGL, const void* WcSD, const void* bcSD,
                       const void* gGL, const void* beGL, const void* gSD, const void* beSD,
                       float* ws) {
    int tid = blockIdx.x * blockDim.x + threadIdx.x;
    int st  = gridDim.x * blockDim.x;
    bool isf = ws[FLAG] != 0.f;
    cvtany(x,    ws + XF,    B*T*V*F, tid, st, isf);
    cvtany(U1,   ws + P_U1,  62,    tid, st, isf);
    cvtany(U2,   ws + P_U2,  310,   tid, st, isf);
    cvtany(U3,   ws + P_U3,  5,     tid, st, isf);
    cvtany(bE,   ws + P_BE,  70225, tid, st, isf);
    cvtany(Ve,   ws + P_VE,  70225, tid, st, isf);
    cvtany(W1,   ws + P_W1,  265,   tid, st, isf);
    cvtany(W2,   ws + P_W2,  1325,  tid, st, isf);
    cvtany(W3,   ws + P_W3,  5,     tid, st, isf);
    cvtany(bS,   ws + P_BS,  3844,  tid, st, isf);
    cvtany(Vs,   ws + P_VS,  3844,  tid, st, isf);
    cvtany(aGL,  ws + P_AGL, 5,     tid, st, isf);
    cvtany(ThGL, ws + P_THGL, 960,  tid, st, isf);
    cvtany(ThSD, ws + P_THSD, 960,  tid, st, isf);
    cvtany(Cheb, ws + P_CHEB, 11532, tid, st, isf);
    cvtany(bcGL, ws + P_BCGL, 64, tid, st, isf);
    cvtany(bcSD, ws + P_BCSD, 64, tid, st, isf);
    cvtany(gGL,  ws + P_GGL,  64, tid, st, isf);
    cvtany(beGL, ws + P_BEGL, 64, tid, st, isf);
    cvtany(gSD,  ws + P_GSD,  64, tid, st, isf);
    cvtany(beSD, ws + P_BESD, 64, tid, st, isf);
    // Wc (FT,FC,KT,1) -> [fc*3+kt][ft]
    for (int i = tid; i < 12288; i += st) {
        int ft = i / 192, r = i - ft * 192;
        float g, s;
        if (isf) { g = ((const float*)WcGL)[i]; s = ((const float*)WcSD)[i]; }
        else     { g = __bfloat162float(((const bf16*)WcGL)[i]);
                   s = __bfloat162float(((const bf16*)WcSD)[i]); }
        ws[P_WTGL + (size_t)r * 64 + ft] = g;
        ws[P_WTSD + (size_t)r * 64 + ft] = s;
    }
}

// -------- t_lhs[b,t,j] = (sum_v x*U1) @ U2 ; one block per (b,t) --------
__global__ void k_tlhs(float* ws) {
    __shared__ float sh[V * F];
    __shared__ float xu[F];
    int blk = blockIdx.x; int b = blk / T, t = blk - b * T;
    int tid = threadIdx.x;
    if (tid < V) {
        float u1v = ws[P_U1 + tid];
        const float* xr = ws + XF + ((size_t)b * T + t) * VF + tid * F;
        #pragma unroll
        for (int f = 0; f < F; f++) sh[tid * F + f] = xr[f] * u1v;
    }
    __syncthreads();
    if (tid < F) {
        float s = 0;
        for (int v = 0; v < V; v++) s += sh[v * F + tid];
        xu[tid] = s;
    }
    __syncthreads();
    if (tid < V) {
        float acc = 0;
        #pragma unroll
        for (int f = 0; f < F; f++) acc += xu[f] * ws[P_U2 + f * V + tid];
        ws[TLHS + ((size_t)b * T + t) * V + tid] = acc;
    }
}

// -------- t_rhs[b,v,t] = sum_f x[b,t,v,f]*U3[f] --------
__global__ void k_trhs(float* ws) {
    int i0 = blockIdx.x * blockDim.x + threadIdx.x;
    int st = gridDim.x * blockDim.x;
    for (int idx = i0; idx < B * V * T; idx += st) {
        int b = idx / (V * T); int r = idx - b * V * T; int v = r / T; int t = r - v * T;
        const float* xr = ws + XF + ((size_t)b * T + t) * VF + v * F;
        float acc = 0;
        #pragma unroll
        for (int f = 0; f < F; f++) acc += xr[f] * ws[P_U3 + f];
        ws[TRHS + idx] = acc;
    }
}

// -------- prod[b,i,k] = sum_j tlhs[b,i,j]*trhs[b,j,k] ; block per (b,i) --------
__global__ __launch_bounds__(256) void k_prod(float* ws) {
    __shared__ float ls[V];
    int blk = blockIdx.x; int b = blk / T, i = blk - b * T;
    int k = threadIdx.x;
    int k2 = min(k + 256, T - 1); bool w2 = (k + 256) < T;
    const float* lr = ws + TLHS + ((size_t)b * T + i) * V;
    const float* rr = ws + TRHS + (size_t)b * V * T;
    if (k < V) ls[k] = lr[k];
    __syncthreads();
    float a0 = 0, a1 = 0;
    for (int j = 0; j < V; j++) {
        float l = ls[j];
        a0 += l * rr[(size_t)j * T + k];
        a1 += l * rr[(size_t)j * T + k2];
    }
    float* o = ws + PRODT + (size_t)b * TT + (size_t)i * T;
    o[k] = a0;
    if (w2) o[k2] = a1;
}

// -------- Sraw = sigmoid(V_e @ prod + b_e), 4 rows per block --------
constexpr int IG = 4, NIG = (T + IG - 1) / IG; // 67
__global__ __launch_bounds__(256) void k_sraw(float* ws) {
    __shared__ float ve[IG * T];    // 4 rows x 265 = 4.2 KB
    int blk = blockIdx.x; int b = blk / NIG; int i0 = (blk - b * NIG) * IG;
    int k = threadIdx.x;
    int k2 = min(k + 256, T - 1); bool w2 = (k + 256) < T;
    const float* pr = ws + PRODT + (size_t)b * TT;
    for (int i = k; i < IG * T; i += 256) {
        int q = i / T, j = i - q * T;
        int ii = min(i0 + q, T - 1);
        ve[i] = ws[P_VE + (size_t)ii * T + j];
    }
    __syncthreads();
    float a0[IG] = {0, 0, 0, 0}, a1[IG] = {0, 0, 0, 0};
    for (int j = 0; j < T; j++) {
        const float* row = pr + (size_t)j * T;
        float r0 = row[k], r1 = row[k2];
        #pragma unroll
        for (int q = 0; q < IG; q++) {
            float v = ve[q * T + j];
            a0[q] += v * r0; a1[q] += v * r1;
        }
    }
    #pragma unroll
    for (int q = 0; q < IG; q++) {
        int i = i0 + q;
        if (i < T) {
            float* o = ws + SRAWT + (size_t)b * TT + (size_t)i * T;
            o[k] = sigmoidf_(a0[q] + ws[P_BE + (size_t)i * T + k]);
            if (w2) o[k2] = sigmoidf_(a1[q] + ws[P_BE + (size_t)i * T + k2]);
        }
    }
}

// -------- column softmax, tiled & coalesced: block per (b, 64-wide k tile) --------
constexpr int KTI = (T + 63) / 64;  // 5
__global__ __launch_bounds__(256) void k_tsm(float* ws) {
    __shared__ float red[4][64];
    __shared__ float cstat[64];
    int blk = blockIdx.x; int b = blk / KTI; int k0 = (blk - b * KTI) * 64;
    int ks = threadIdx.x & 63; int isub = threadIdx.x >> 6;
    int k = k0 + ks; bool act = k < T;
    float* S = ws + SRAWT + (size_t)b * TT;
    float m = -1e30f;
    if (act) for (int i = isub; i < T; i += 4) m = fmaxf(m, S[(size_t)i * T + k]);
    red[isub][ks] = m;
    __syncthreads();
    if (isub == 0)
        cstat[ks] = fmaxf(fmaxf(red[0][ks], red[1][ks]), fmaxf(red[2][ks], red[3][ks]));
    __syncthreads();
    m = cstat[ks];
    float s = 0;
    if (act) for (int i = isub; i < T; i += 4) s += expf(S[(size_t)i * T + k] - m);
    __syncthreads();
    red[isub][ks] = s;
    __syncthreads();
    if (isub == 0)
        cstat[ks] = 1.f / (red[0][ks] + red[1][ks] + red[2][ks] + red[3][ks]);
    __syncthreads();
    float inv = cstat[ks];
    if (act) for (int i = isub; i < T; i += 4) {
        size_t o = (size_t)i * T + k;
        S[o] = expf(S[o] - m) * inv;
    }
}

// -------- y[b,p,t] = sum_s x_flat[b,p,s]*TAtt[b,s,t]; 8 p per block --------
constexpr int PG = 8, NPG = (VF + PG - 1) / PG; // 39
__global__ __launch_bounds__(256) void k_y(float* ws) {
    __shared__ float xs[T * PG];    // 265 x 8 = 8.3 KB
    int blk = blockIdx.x; int b = blk / NPG; int p0 = (blk - b * NPG) * PG;
    int t = threadIdx.x;
    int t2 = min(t + 256, T - 1); bool w2 = (t + 256) < T;
    const float* xb = ws + XF + (size_t)b * TVF;
    const float* ta = ws + SRAWT + (size_t)b * TT;
    for (int i = threadIdx.x; i < T * PG; i += 256) {
        int s = i >> 3, j = i & 7;   // tail lanes read past x into TLHS: finite, unused
        xs[i] = xb[(size_t)s * VF + p0 + j];
    }
    __syncthreads();
    float a0[PG], a1[PG];
    #pragma unroll
    for (int j = 0; j < PG; j++) { a0[j] = 0; a1[j] = 0; }
    for (int s = 0; s < T; s++) {
        float ta0 = ta[(size_t)s * T + t];
        float ta1 = ta[(size_t)s * T + t2];
        const float* xr = xs + s * PG;
        #pragma unroll
        for (int j = 0; j < PG; j++) {  // broadcast LDS reads (free)
            float xv = xr[j];
            a0[j] += xv * ta0; a1[j] += xv * ta1;
        }
    }
    float* yb = ws + YBUF + (size_t)b * VF * T;
    #pragma unroll
    for (int j = 0; j < PG; j++) {
        if (p0 + j < VF) {
            yb[(size_t)(p0 + j) * T + t] = a0[j];
            if (w2) yb[(size_t)(p0 + j) * T + t2] = a1[j];
        }
    }
}

// -------- xw[b,v,f] = sum_t x_TAtt[b,t,v,f]*W1[t]; block per (b, 64-wide p tile) --------
constexpr int PTI = (VF + 63) / 64;  // 5
__global__ __launch_bounds__(256) void k_xw(float* ws) {
    __shared__ float red[4][64];
    __shared__ float w1s[T];
    int blk = blockIdx.x; int b = blk / PTI; int p0 = (blk - b * PTI) * 64;
    int ps = threadIdx.x & 63; int tsub = threadIdx.x >> 6;
    int p = p0 + ps; bool act = p < VF;
    for (int i = threadIdx.x; i < T; i += 256) w1s[i] = ws[P_W1 + i];
    const float* yb = ws + YBUF + (size_t)b * TVF;
    __syncthreads();
    float acc = 0;
    if (act) for (int t = tsub; t < T; t += 4) acc += yb[(size_t)t * VF + p] * w1s[t];
    red[tsub][ps] = acc;
    __syncthreads();
    if (tsub == 0 && act)
        ws[XWOF + (size_t)b * VF + p] = red[0][ps] + red[1][ps] + red[2][ps] + red[3][ps];
}

// -------- merged s_lhs + s_rhs --------
__global__ void k_ssr(float* ws) {
    int i0 = blockIdx.x * blockDim.x + threadIdx.x;
    int st = gridDim.x * blockDim.x;
    for (int idx = i0; idx < B * V * T; idx += st) {   // s_lhs[b,v,j]
        int b = idx / (V * T); int r = idx - b * V * T; int v = r / T; int j = r - v * T;
        float acc = 0;
        #pragma unroll
        for (int f = 0; f < F; f++)
            acc += ws[XWOF + (size_t)b * VF + v * F + f] * ws[P_W2 + (size_t)f * T + j];
        ws[SLHS + idx] = acc;
    }
    for (int idx = i0; idx < B * T * V; idx += st) {   // s_rhs[b,t,v]
        int b = idx / (T * V); int r = idx - b * T * V; int t = r / V; int v = r - t * V;
        const float* yr = ws + YBUF + (size_t)b * TVF + (size_t)t * VF + v * F;
        float acc = 0;
        #pragma unroll
        for (int f = 0; f < F; f++) acc += yr[f] * ws[P_W3 + f];
        ws[SRHS + idx] = acc;
    }
}

// -------- sp[b,i,k] = sum_j slhs[b,i,j]*srhs[b,j,k] (grid-stride, coalesced) --------
__global__ void k_sprod(float* ws) {
    int i0 = blockIdx.x * blockDim.x + threadIdx.x;
    int st = gridDim.x * blockDim.x;
    for (int idx = i0; idx < B * VV; idx += st) {
        int b = idx / VV; int r = idx - b * VV; int i = r / V; int k = r - i * V;
        const float* sl = ws + SLHS + (size_t)b * V * T + (size_t)i * T;
        const float* sr = ws + SRHS + (size_t)b * T * V;
        float acc = 0;
        for (int j = 0; j < T; j++) acc += sl[j] * sr[(size_t)j * V + k];
        ws[SPROD + idx] = acc;
    }
}

// -------- SAtt = colsoftmax(sigmoid(Vs@sp + bs)) ; block per b (small) --------
__global__ __launch_bounds__(256) void k_satt(float* ws) {
    __shared__ float sp[VV];
    __shared__ float s2[VV];
    int b = blockIdx.x, tid = threadIdx.x;
    for (int i = tid; i < VV; i += 256) sp[i] = ws[SPROD + (size_t)b * VV + i];
    __syncthreads();
    for (int idx = tid; idx < VV; idx += 256) {
        int i = idx / V, k = idx - i * V;
        float acc = 0;
        for (int j = 0; j < V; j++) acc += ws[P_VS + (size_t)i * V + j] * sp[j * V + k];
        s2[idx] = sigmoidf_(acc + ws[P_BS + idx]);
    }
    __syncthreads();
    if (tid < V) {
        int k = tid;
        float m = -1e30f;
        for (int i = 0; i < V; i++) m = fmaxf(m, s2[i * V + k]);
        float sum = 0;
        for (int i = 0; i < V; i++) sum += expf(s2[i * V + k] - m);
        float inv = 1.f / sum;
        for (int i = 0; i < V; i++)
            ws[SATT + (size_t)b * VV + i * V + k] = expf(s2[i * V + k] - m) * inv;
    }
}

// -------- per-(b,t) fused graph-learning + Chebyshev convs -> full GCN buffer --------
__global__ __launch_bounds__(256) void k_cheb(float* ws) {
    __shared__ float xt[VF];
    __shared__ float sa[VV];
    __shared__ float bufA[VV];   // Sg -> T2 -> M2 -> (sel1 Mk)
    __shared__ float bufB[VV];   // A -> L -> M1
    __shared__ float rhs[VF];
    __shared__ float rsum[64];
    __shared__ float ag[8];
    int blk = blockIdx.x; int b = blk / T, t = blk - b * T;
    int tid = threadIdx.x;
    for (int i = tid; i < VF; i += 256) xt[i] = ws[XF + (size_t)b * TVF + (size_t)t * VF + i];
    if (tid < F) ag[tid] = ws[P_AGL + tid];
    for (int i = tid; i < VV; i += 256) sa[i] = ws[SATT + (size_t)b * VV + i];
    __syncthreads();
    for (int idx = tid; idx < VV; idx += 256) {   // Sg = exp(|xu-xv|.a)
        int u = idx / V, v = idx - u * V;
        float acc = 0;
        #pragma unroll
        for (int f = 0; f < F; f++) acc += fabsf(xt[u * F + f] - xt[v * F + f]) * ag[f];
        bufA[idx] = expf(acc);
    }
    __syncthreads();
    if (tid < V) { float s = 0; for (int v = 0; v < V; v++) s += bufA[tid * V + v]; rsum[tid] = s; }
    __syncthreads();
    for (int idx = tid; idx < VV; idx += 256) {   // A = min(Sgn, Sgn^T)
        int u = idx / V, v = idx - u * V;
        float a = bufA[u * V + v] / rsum[u];
        float s = bufA[v * V + u] / rsum[v];
        bufB[idx] = fminf(a, s);
    }
    __syncthreads();
    if (tid < V) { float s = 0; for (int v = 0; v < V; v++) s += bufB[tid * V + v]; rsum[tid] = s; }
    __syncthreads();
    for (int idx = tid; idx < VV; idx += 256) {   // L = diag(d-1) - A
        int u = idx / V, v = idx - u * V;
        bufB[idx] = ((u == v) ? (rsum[u] - 1.f) : 0.f) - bufB[idx];
    }
    __syncthreads();
    {   // T2 = 2 L@L - I, register-tiled 4x4 (2 MAC per LDS read)
        int tu = tid >> 4, tv = tid & 15;
        float acc4[4][4];
        #pragma unroll
        for (int a = 0; a < 4; a++)
            #pragma unroll
            for (int c = 0; c < 4; c++) acc4[a][c] = 0.f;
        for (int k = 0; k < V; k++) {
            float av[4], bv[4];
            #pragma unroll
            for (int d = 0; d < 4; d++) {
                int u = 4 * tu + d;
                av[d] = (u < V) ? bufB[u * V + k] : 0.f;
                int v = 4 * tv + d;
                bv[d] = (v < V) ? bufB[k * V + v] : 0.f;
            }
            #pragma unroll
            for (int a = 0; a < 4; a++)
                #pragma unroll
                for (int c = 0; c < 4; c++) acc4[a][c] += av[a] * bv[c];
        }
        __syncthreads();
        #pragma unroll
        for (int a = 0; a < 4; a++) {
            int u = 4 * tu + a;
            if (u >= V) continue;
            #pragma unroll
            for (int c = 0; c < 4; c++) {
                int v = 4 * tv + c;
                if (v >= V) continue;
                bufA[u * V + v] = 2.f * acc4[a][c] - ((u == v) ? 1.f : 0.f);
            }
        }
    }
    __syncthreads();
    for (int idx = tid; idx < VV; idx += 256) {   // M1 = L.SA, M2 = T2.SA (elementwise)
        float s = sa[idx];
        bufB[idx] *= s;
        bufA[idx] *= s;
    }
    __syncthreads();
    for (int sel = 0; sel < 2; sel++) {
        float zreg[16];
        #pragma unroll
        for (int i = 0; i < 16; i++) zreg[i] = 0.f;
        const float* Th = ws + (sel ? P_THSD : P_THGL);
        for (int kk = 0; kk < Kc; kk++) {
            if (sel == 1 && kk > 0) {   // stage Mk = C_kk . SA into bufA
                const float* C = ws + P_CHEB + (size_t)kk * VV;
                for (int idx = tid; idx < VV; idx += 256) bufA[idx] = C[idx] * sa[idx];
                __syncthreads();
            }
            for (int idx = tid; idx < VF; idx += 256) {  // rhs[u,f] = sum_v M[v,u]*x[v,f]
                int u = idx / F, f = idx - u * F;
                float acc = 0;
                if (kk == 0) {
                    acc = sa[u * V + u] * xt[u * F + f];   // T0 = I (both GL and SD)
                } else {
                    const float* M = (sel == 0 && kk == 1) ? bufB : bufA;
                    for (int v = 0; v < V; v++) acc += M[v * V + u] * xt[v * F + f];
                }
                rhs[idx] = acc;
            }
            __syncthreads();
            #pragma unroll
            for (int i = 0; i < 16; i++) {              // z += rhs @ Th (registers)
                int idx = i * 256 + tid;
                if (idx < V * FC) {
                    int u = idx >> 6, o = idx & 63;
                    float acc = 0;
                    #pragma unroll
                    for (int f = 0; f < F; f++) acc += rhs[u * F + f] * Th[(kk * F + f) * FC + o];
                    zreg[i] += acc;
                }
            }
            __syncthreads();   // protect rhs before next kk overwrites it
        }
        float* outp = ws + GCN + (((size_t)sel * B + b) * T + t) * V * FC;
        #pragma unroll
        for (int i = 0; i < 16; i++) {
            int idx = i * 256 + tid;
            if (idx < V * FC) outp[idx] = fmaxf(zreg[i], 0.f);
        }
    }
}

// -------- conv(3x1) + bias + layernorm(FT) + store; block per (sel, b, t) --------
// Register-tiled GEMM (proven): thread (tf,tv) owns a 4ft x 4v tile; slots
// (t-1,t,t+1) staged TRANSPOSED [kt][c][v+pad] -> lane-distinct ds_read_b128.
// Round-6 fixes for the latency-bound signature (FETCH 198MB @ 715GB/s, occ 23%):
//  - LN-reduce scratch UNIONED into ring_s (dead after GEMM): LDS 61->51KB -> 3 blk/CU
//  - float4 stage loads (4x fewer global instrs, 4x inflight bytes)
//  - XCD-aware swizzle: neighboring-t blocks (sharing 2/3 slots) land on one L2
constexpr int RST = 68;   // transposed row stride: 16B-aligned, 2-way banks (free)
__global__ __launch_bounds__(256) void k_conv(const float* ws, void* outv) {
    __shared__ float ring_s[3 * 64 * RST];          // 51 KiB; reused as LN scratch
    float* red0 = ring_s;                           // [16][64] sum partials
    float* red1 = ring_s + 1024;                    // [16][64] sumsq partials
    float* mus  = ring_s + 2048;
    float* rsg  = ring_s + 2112;
    int blk = blockIdx.x;
    {   // XCD swizzle: 8480 % 8 == 0 -> bijective chunked remap
        constexpr int CPX = 2 * BT / 8;             // 1060
        blk = (blk & 7) * CPX + (blk >> 3);
    }
    int sel = (blk >= BT) ? 1 : 0;
    int r0  = blk - sel * BT;
    int b = r0 / T, t = r0 - b * T;
    int tid = threadIdx.x;
    int tv = tid & 15, tf = tid >> 4;             // v-quad, ft-quad
    bool isf = ws[FLAG] != 0.f;
    const float4* wt4 = (const float4*)(ws + (sel ? P_WTSD : P_WTGL)); // [c*3+kt][ft/4]
    const float* ringb = ws + GCN + (((size_t)sel * B + b) * T + (t - 1)) * V * FC;
    // zero pad columns (v=62..67): no v-bounds checks in main loop
    for (int i = tid; i < 3 * 64 * (RST - V); i += 256) {
        int sc = i / (RST - V), p = i - sc * (RST - V);
        ring_s[sc * RST + V + p] = 0.f;
    }
    // stage 3 slots (float4 loads, transposed scatter [v][c] -> [c][v]); edges zeroed
    for (int i = tid; i < 3 * V * FC / 4; i += 256) {
        int i4 = i * 4;
        int s = i4 / (V * FC), e = i4 - s * (V * FC);
        int v = e >> 6, c = e & 63;                // c is 4-aligned (V*FC % 4 == 0)
        int tglob = t - 1 + s;
        float4 val = make_float4(0.f, 0.f, 0.f, 0.f);
        if (tglob >= 0 && tglob < T) val = *(const float4*)(ringb + i4);
        float* dst = ring_s + (s * 64 + c) * RST + v;
        dst[0] = val.x; dst[RST] = val.y; dst[2 * RST] = val.z; dst[3 * RST] = val.w;
    }
    __syncthreads();

    float acc[4][4];                              // [ft-sub a][v-sub d]
    #pragma unroll
    for (int a = 0; a < 4; a++)
        #pragma unroll
        for (int d = 0; d < 4; d++) acc[a][d] = 0.f;

    const float* rbase = ring_s + 4 * tv;
    #define LD4_(dst, src) { float4 _t4 = (src); dst[0] = _t4.x; dst[1] = _t4.y; dst[2] = _t4.z; dst[3] = _t4.w; }
    #pragma unroll 4
    for (int c = 0; c < 64; c++) {
        float w0[4], w1[4], w2[4], q0[4], q1[4], q2[4];
        LD4_(w0, wt4[(c * 3 + 0) * 16 + tf]);
        LD4_(w1, wt4[(c * 3 + 1) * 16 + tf]);
        LD4_(w2, wt4[(c * 3 + 2) * 16 + tf]);
        LD4_(q0, *(const float4*)(rbase + c * RST));
        LD4_(q1, *(const float4*)(rbase + (64 + c) * RST));
        LD4_(q2, *(const float4*)(rbase + (128 + c) * RST));
        #pragma unroll
        for (int a = 0; a < 4; a++)
            #pragma unroll
            for (int d = 0; d < 4; d++)
                acc[a][d] += w0[a] * q0[d] + w1[a] * q1[d] + w2[a] * q2[d];
    }
    #undef LD4_

    // epilogue: + bias, layernorm over ft (LDS tree across 16 tf-groups), store
    float bcs[4], ggs[4], bbs[4];
    #pragma unroll
    for (int a = 0; a < 4; a++) {
        bcs[a] = ws[(sel ? P_BCSD : P_BCGL) + 4 * tf + a];
        ggs[a] = ws[(sel ? P_GSD  : P_GGL)  + 4 * tf + a];
        bbs[a] = ws[(sel ? P_BESD : P_BEGL) + 4 * tf + a];
    }
    float ps[4] = {0, 0, 0, 0}, pq[4] = {0, 0, 0, 0};
    #pragma unroll
    for (int a = 0; a < 4; a++)
        #pragma unroll
        for (int d = 0; d < 4; d++) {
            float v = acc[a][d] + bcs[a];
            acc[a][d] = v;
            ps[d] += v; pq[d] += v * v;
        }
    __syncthreads();    // all GEMM reads of ring_s done; safe to reuse as scratch
    #pragma unroll
    for (int d = 0; d < 4; d++) {
        red0[tf * 64 + 4 * tv + d] = ps[d];
        red1[tf * 64 + 4 * tv + d] = pq[d];
    }
    __syncthreads();
    if (tid < 64) {
        float s = 0.f, q = 0.f;
        #pragma unroll
        for (int g = 0; g < 16; g++) { s += red0[g * 64 + tid]; q += red1[g * 64 + tid]; }
        float mu  = s * (1.f / 64.f);
        float var = q * (1.f / 64.f) - mu * mu;
        mus[tid] = mu; rsg[tid] = rsqrtf(var + 1e-5f);
    }
    __syncthreads();
    size_t obase = (size_t)sel * B * FT * T * V;
    #pragma unroll
    for (int a = 0; a < 4; a++) {
        int ft = 4 * tf + a;
        size_t orow = obase + (((size_t)(b * FT + ft)) * T + t) * V;
        #pragma unroll
        for (int d = 0; d < 4; d++) {
            int v = 4 * tv + d;
            if (v < V) {
                float val = (acc[a][d] - mus[v]) * rsg[v] * ggs[a] + bbs[a];
                if (isf) ((float*)outv)[orow + v] = val;
                else     ((bf16*)outv)[orow + v] = __float2bfloat16(val);
            }
        }
    }
}

extern "C" void kernel_launch(void* const* d_in, const int* in_sizes, int n_in,
                              void* d_out, int out_size, void* d_ws, size_t ws_size,
                              hipStream_t stream) {
    float* ws = (float*)d_ws;
    hipLaunchKernelGGL(k_dtype, dim3(1), dim3(256), 0, stream, d_in[0], ws);
    hipLaunchKernelGGL(k_prep, dim3(256), dim3(256), 0, stream,
                       d_in[0], d_in[1], d_in[2], d_in[3], d_in[4], d_in[5], d_in[6],
                       d_in[7], d_in[8], d_in[9], d_in[10], d_in[11], d_in[12], d_in[13],
                       d_in[14], d_in[15], d_in[16], d_in[17], d_in[18], d_in[19],
                       d_in[20], d_in[21], d_in[22], ws);
    hipLaunchKernelGGL(k_tlhs,  dim3(BT),        dim3(64),  0, stream, ws);
    hipLaunchKernelGGL(k_trhs,  dim3(512),       dim3(256), 0, stream, ws);
    hipLaunchKernelGGL(k_prod,  dim3(BT),        dim3(256), 0, stream, ws);
    hipLaunchKernelGGL(k_sraw,  dim3(B * NIG),   dim3(256), 0, stream, ws);
    hipLaunchKernelGGL(k_tsm,   dim3(B * KTI),   dim3(256), 0, stream, ws);
    hipLaunchKernelGGL(k_y,     dim3(B * NPG),   dim3(256), 0, stream, ws);
    hipLaunchKernelGGL(k_xw,    dim3(B * PTI),   dim3(256), 0, stream, ws);
    hipLaunchKernelGGL(k_ssr,   dim3(512),       dim3(256), 0, stream, ws);
    hipLaunchKernelGGL(k_sprod, dim3(241),       dim3(256), 0, stream, ws);
    hipLaunchKernelGGL(k_satt,  dim3(B),         dim3(256), 0, stream, ws);
    hipLaunchKernelGGL(k_cheb,  dim3(BT),        dim3(256), 0, stream, ws);
    hipLaunchKernelGGL(k_conv,  dim3(2 * BT),    dim3(256), 0, stream, ws, d_out);
}